// Round 8
// baseline (48093.976 us; speedup 1.0000x reference)
//
#include <hip/hip_runtime.h>
#include <math.h>

// Problem constants (fixed by setup_inputs)
#define NN 4096      // N samples
#define DD 256       // flat endo dim (8 vars * 32)
#define NV 8         // vars
#define VD 32        // per-var dim
#define NB 128       // GJ block size
#define NBLK (NN/NB) // 32
#define NTRI (NBLK*(NBLK+1)/2)  // 528

// fp32-GEMM output ownership mapping (bank-conflict-free)
#define RMAP(ty,u) ((ty)*4 + (((u)>>2)<<6) + ((u)&3))
#define CMAP(tx,v) ((tx)*4 + (((v)>>2)<<6) + ((v)&3))

typedef __attribute__((ext_vector_type(8))) short bf16x8;
typedef __attribute__((ext_vector_type(4))) float f32x4;

#define AS1(p) ((const __attribute__((address_space(1))) void*)(p))
#define AS3(p) ((__attribute__((address_space(3))) void*)(p))

__device__ __forceinline__ void stage16(const ushort* g, ushort* l){
  __builtin_amdgcn_global_load_lds(AS1(g), AS3(l), 16, 0, 0);
}

__device__ __forceinline__ ushort f2bf(float x){
  uint u = __float_as_uint(x);
  u += 0x7FFFu + ((u >> 16) & 1u);
  return (ushort)(u >> 16);
}
__device__ __forceinline__ float bf2f(ushort h){ return __uint_as_float(((uint)h) << 16); }

// triangular block map: p -> (bi >= bj)
__device__ __forceinline__ void tri_map(int p, int& bi, int& bj){
  int b = (int)((sqrtf(8.0f * (float)p + 1.0f) - 1.0f) * 0.5f);
  while ((b + 1) * (b + 2) / 2 <= p) b++;
  while (b * (b + 1) / 2 > p) b--;
  bi = b; bj = p - b * (b + 1) / 2;
}

// ---------------- helpers ----------------
__device__ __forceinline__ void block_atomic_add(float v, float* red, float* dst){
  #pragma unroll
  for (int off = 32; off > 0; off >>= 1) v += __shfl_down(v, off, 64);
  const int lane = threadIdx.x & 63;
  const int w = threadIdx.x >> 6;
  if (lane == 0) red[w] = v;
  __syncthreads();
  if (threadIdx.x == 0) atomicAdd(dst, red[0] + red[1] + red[2] + red[3]);
  __syncthreads();
}

// shared staging macros for the bf16 MFMA GEMM main loops
#define STAGE_AB(tAp, tBp, kk) do { \
  _Pragma("unroll") \
  for (int p_ = 0; p_ < 2; p_++){ \
    const int row_ = p_*64 + (t >> 2); \
    const int lo_ = row_*32 + sch; \
    stage16(Ah + (size_t)(r0 + row_) * NN + (kk) + sch, (tAp) + lo_); \
    stage16(Bh + (size_t)(c0 + row_) * NN + (kk) + sch, (tBp) + lo_); \
  } } while(0)

#define MFMA_STEP(tAp, tBp) do { \
  bf16x8 ah_[4], bh_[4]; \
  _Pragma("unroll") \
  for (int i_ = 0; i_ < 4; i_++){ \
    ah_[i_] = *(const bf16x8*)&(tAp)[(wr*64 + i_*16 + lm)*32 + quad*8]; \
    bh_[i_] = *(const bf16x8*)&(tBp)[(wc*64 + i_*16 + lm)*32 + quad*8]; \
  } \
  _Pragma("unroll") \
  for (int i_ = 0; i_ < 4; i_++) \
    _Pragma("unroll") \
    for (int j_ = 0; j_ < 4; j_++) \
      acc[i_][j_] = __builtin_amdgcn_mfma_f32_16x16x32_bf16(ah_[i_], bh_[j_], acc[i_][j_], 0, 0, 0); \
  } while(0)

// counted-vmcnt pipelined step (T3+T4): raw barrier, NO vmcnt(0) drain in main loop.
#define PIPE_WAIT_BAR(N) do { \
  asm volatile("s_waitcnt vmcnt(" #N ")" ::: "memory"); \
  __builtin_amdgcn_s_barrier(); \
  } while(0)
#define PIPE_BAR() do { \
  asm volatile("" ::: "memory"); \
  __builtin_amdgcn_s_barrier(); \
  asm volatile("" ::: "memory"); \
  } while(0)

// Depth-3 ring main loop over NN/32 = 128 K-steps.
#define PIPE_MAIN_LOOP() do { \
  STAGE_AB(shb + 0*8192, shb + 0*8192 + 4096, 0); \
  STAGE_AB(shb + 1*8192, shb + 1*8192 + 4096, 32); \
  STAGE_AB(shb + 2*8192, shb + 2*8192 + 4096, 64); \
  int cur = 0; \
  _Pragma("unroll 1") \
  for (int step = 0; step < 125; step++){ \
    ushort* tA = shb + cur*8192; ushort* tB = tA + 4096; \
    PIPE_WAIT_BAR(8); \
    MFMA_STEP(tA, tB); \
    PIPE_BAR(); \
    STAGE_AB(tA, tB, (step+3)*32); \
    cur++; if (cur == 3) cur = 0; \
  } \
  { ushort* tA = shb + cur*8192; ushort* tB = tA + 4096; \
    PIPE_WAIT_BAR(8); MFMA_STEP(tA, tB); cur++; if (cur == 3) cur = 0; } \
  { ushort* tA = shb + cur*8192; ushort* tB = tA + 4096; \
    PIPE_WAIT_BAR(4); MFMA_STEP(tA, tB); cur++; if (cur == 3) cur = 0; } \
  { ushort* tA = shb + cur*8192; ushort* tB = tA + 4096; \
    PIPE_WAIT_BAR(0); MFMA_STEP(tA, tB); } \
  } while(0)

// ---------------- small utility kernels ----------------
__global__ void k_zero(float* p, int n){
  int i = blockIdx.x * blockDim.x + threadIdx.x;
  if (i < n) p[i] = 0.f;
}

__global__ void k_norms(const float* __restrict__ z, const float* __restrict__ zz,
                        const float* __restrict__ stdn,
                        float* __restrict__ stdsq, float* __restrict__ zrs,
                        float* __restrict__ nzz, float* __restrict__ nz8){
  int t = blockIdx.x * blockDim.x + threadIdx.x;
  if (t >= NN * NV) return;
  int i = t / NV, v = t % NV;
  const float* zp  = z  + (size_t)i * DD + v * VD;
  const float* zzp = zz + (size_t)i * DD + v * VD;
  float s1 = 0.f, s2 = 0.f, s2z = 0.f;
  #pragma unroll
  for (int k = 0; k < VD; k++){
    float a = zp[k];  s1 += a; s2 += a * a;
    float b = zzp[k]; s2z += b * b;
  }
  zrs[(size_t)i * NV + v] = s1;
  nz8[(size_t)v * NN + i] = s2;
  nzz[(size_t)v * NN + i] = s2z;
  if (v == 0){
    float s = 0.f;
    #pragma unroll
    for (int u = 0; u < NV; u++){ float a = stdn[(size_t)i * NV + u]; s += a * a; }
    stdsq[i] = s;
  }
}

__global__ void k_rownorm(const float* __restrict__ nz8, float* __restrict__ nrmz){
  int i = blockIdx.x * blockDim.x + threadIdx.x;
  if (i < NN){
    float s = 0.f;
    #pragma unroll
    for (int v = 0; v < NV; v++) s += nz8[(size_t)v * NN + i];
    nrmz[i] = s;
  }
}

__global__ __launch_bounds__(256) void k_nll(const float* __restrict__ x,
                                             const float* __restrict__ xx,
                                             float* __restrict__ slots){
  __shared__ float red[4];
  float s = 0.f;
  const int total = NN * DD;
  for (int i = (blockIdx.x * 256 + threadIdx.x) * 4; i < total; i += gridDim.x * 256 * 4){
    float4 a = *(const float4*)(x + i);
    float4 b = *(const float4*)(xx + i);
    float d0 = b.x - a.x, d1 = b.y - a.y, d2 = b.z - a.z, d3 = b.w - a.w;
    s += d0*d0 + d1*d1 + d2*d2 + d3*d3;
  }
  block_atomic_add(s, red, slots + 3);
}

// ---------------- first (exo-free) MMD term ----------------
__global__ __launch_bounds__(256) void k_sqq(const float* __restrict__ z,
                                             const float* __restrict__ nrm,
                                             float* __restrict__ slots){
  __shared__ float Xr[128 * 33];
  __shared__ float Xc[128 * 33];
  __shared__ float red[4];
  int bi, bj; tri_map(blockIdx.x, bi, bj);
  const int r0 = bi * 128, c0 = bj * 128;
  const float wgt = (bi != bj) ? 2.f : 1.f;
  const int t = threadIdx.x;
  const int tx = t & 15, ty = t >> 4;
  const int lrow = t >> 1, lh = t & 1;
  float acc[8][8];
  #pragma unroll
  for (int u = 0; u < 8; u++)
    #pragma unroll
    for (int v = 0; v < 8; v++) acc[u][v] = 0.f;
  for (int ks = 0; ks < DD; ks += 32){
    const float* pr = z + (size_t)(r0 + lrow) * DD + ks + lh * 16;
    const float* pc = z + (size_t)(c0 + lrow) * DD + ks + lh * 16;
    float* dr = &Xr[lrow * 33 + lh * 16];
    float* dc = &Xc[lrow * 33 + lh * 16];
    #pragma unroll
    for (int u = 0; u < 4; u++){
      float4 a = ((const float4*)pr)[u];
      dr[4*u+0] = a.x; dr[4*u+1] = a.y; dr[4*u+2] = a.z; dr[4*u+3] = a.w;
      float4 b = ((const float4*)pc)[u];
      dc[4*u+0] = b.x; dc[4*u+1] = b.y; dc[4*u+2] = b.z; dc[4*u+3] = b.w;
    }
    __syncthreads();
    #pragma unroll
    for (int kk = 0; kk < 32; kk++){
      float a[8], b[8];
      #pragma unroll
      for (int u = 0; u < 8; u++) a[u] = Xr[RMAP(ty,u)*33 + kk];
      #pragma unroll
      for (int v = 0; v < 8; v++) b[v] = Xc[CMAP(tx,v)*33 + kk];
      #pragma unroll
      for (int u = 0; u < 8; u++)
        #pragma unroll
        for (int v = 0; v < 8; v++) acc[u][v] += a[u] * b[v];
    }
    __syncthreads();
  }
  float s = 0.f;
  #pragma unroll 1
  for (int u = 0; u < 8; u++){
    const float ni = nrm[r0 + RMAP(ty,u)];
    #pragma unroll 1
    for (int v = 0; v < 8; v++)
      s += __expf(-(ni + nrm[c0 + CMAP(tx,v)] - 2.f * acc[u][v]) * (1.f/2048.f));
  }
  block_atomic_add(s * wgt, red, slots + 0);
}

__global__ __launch_bounds__(256) void k_spp_sqp(const float* __restrict__ stdn,
                                                 const float* __restrict__ stdsq,
                                                 const float* __restrict__ zrs,
                                                 const float* __restrict__ nrmz,
                                                 float* __restrict__ slots){
  __shared__ float sI[128*9], sJ[128*9], zI[128*9];
  __shared__ float qI[128], qJ[128], nI[128];
  __shared__ float red[4];
  const int r0 = blockIdx.y * 128, c0 = blockIdx.x * 128;
  const int t = threadIdx.x;
  if (t < 128){
    #pragma unroll
    for (int v = 0; v < 8; v++){
      sI[t*9+v] = stdn[(size_t)(r0+t)*NV + v];
      sJ[t*9+v] = stdn[(size_t)(c0+t)*NV + v];
      zI[t*9+v] = zrs[(size_t)(r0+t)*NV + v];
    }
    qI[t] = stdsq[r0+t]; qJ[t] = stdsq[c0+t]; nI[t] = nrmz[r0+t];
  }
  __syncthreads();
  const int tx = t & 15, ty = t >> 4;
  float spp = 0.f, sqp = 0.f;
  #pragma unroll 1
  for (int u = 0; u < 8; u++){
    int i = ty + 16*u;
    #pragma unroll 1
    for (int v = 0; v < 8; v++){
      int j = tx + 16*v;
      float dpp = 0.f, dqp = 0.f;
      #pragma unroll
      for (int k = 0; k < 8; k++){
        float sj = sJ[j*9+k];
        dpp += sI[i*9+k] * sj;
        dqp += zI[i*9+k] * sj;
      }
      spp += __expf(-(qI[i] + qJ[j] - 2.f*dpp) * (1.f/64.f));
      sqp += __expf(-(nI[i] + 32.f*qJ[j] - 2.f*dqp) * (1.f/2048.f));
    }
  }
  block_atomic_add(spp, red, slots + 1);
  block_atomic_add(sqp, red, slots + 2);
}

// ---------------- RBF Gram matrix build (K=32, fp32 out) ----------------
__global__ __launch_bounds__(256) void k_rbf(const float* __restrict__ Xr_,
                                             const float* __restrict__ Xc_,
                                             const float* __restrict__ nr,
                                             const float* __restrict__ nc,
                                             float lam, float* __restrict__ M){
  __shared__ float Xr[128 * 33];
  __shared__ float Xc[128 * 33];
  const int r0 = blockIdx.y * 128, c0 = blockIdx.x * 128;
  const int t = threadIdx.x;
  const int tx = t & 15, ty = t >> 4;
  const int lrow = t >> 1, lh = t & 1;
  {
    const float* pr = Xr_ + (size_t)(r0 + lrow) * DD + lh * 16;
    const float* pc = Xc_ + (size_t)(c0 + lrow) * DD + lh * 16;
    float* dr = &Xr[lrow * 33 + lh * 16];
    float* dc = &Xc[lrow * 33 + lh * 16];
    #pragma unroll
    for (int u = 0; u < 4; u++){
      float4 a = ((const float4*)pr)[u];
      dr[4*u+0]=a.x; dr[4*u+1]=a.y; dr[4*u+2]=a.z; dr[4*u+3]=a.w;
      float4 b = ((const float4*)pc)[u];
      dc[4*u+0]=b.x; dc[4*u+1]=b.y; dc[4*u+2]=b.z; dc[4*u+3]=b.w;
    }
  }
  __syncthreads();
  #pragma unroll 1
  for (int u = 0; u < 8; u++){
    const int gi = r0 + RMAP(ty,u);
    const float* xi = &Xr[RMAP(ty,u)*33];
    const float ni = nr[gi];
    float vals[8];
    #pragma unroll 1
    for (int v = 0; v < 8; v++){
      const int gj = c0 + CMAP(tx,v);
      const float* xj = &Xc[CMAP(tx,v)*33];
      float d = 0.f;
      #pragma unroll
      for (int k = 0; k < 32; k++) d += xi[k] * xj[k];
      float e = __expf(-(ni + nc[gj] - 2.f*d) * (1.f/32.f));
      if (gi == gj) e += lam;
      vals[v] = e;
    }
    float* pd = M + (size_t)gi * NN + c0 + tx*4;
    *(float4*)pd        = make_float4(vals[0], vals[1], vals[2], vals[3]);
    *(float4*)(pd + 64) = make_float4(vals[4], vals[5], vals[6], vals[7]);
  }
}

// ---------------- RBF Gram matrix build (K=32, bf16 out, no diag reg) ----------------
__global__ __launch_bounds__(256) void k_rbf16(const float* __restrict__ Xr_,
                                               const float* __restrict__ Xc_,
                                               const float* __restrict__ nr,
                                               const float* __restrict__ nc,
                                               ushort* __restrict__ Mh){
  __shared__ float Xr[128 * 33];
  __shared__ float Xc[128 * 33];
  const int r0 = blockIdx.y * 128, c0 = blockIdx.x * 128;
  const int t = threadIdx.x;
  const int tx = t & 15, ty = t >> 4;
  const int lrow = t >> 1, lh = t & 1;
  {
    const float* pr = Xr_ + (size_t)(r0 + lrow) * DD + lh * 16;
    const float* pc = Xc_ + (size_t)(c0 + lrow) * DD + lh * 16;
    float* dr = &Xr[lrow * 33 + lh * 16];
    float* dc = &Xc[lrow * 33 + lh * 16];
    #pragma unroll
    for (int u = 0; u < 4; u++){
      float4 a = ((const float4*)pr)[u];
      dr[4*u+0]=a.x; dr[4*u+1]=a.y; dr[4*u+2]=a.z; dr[4*u+3]=a.w;
      float4 b = ((const float4*)pc)[u];
      dc[4*u+0]=b.x; dc[4*u+1]=b.y; dc[4*u+2]=b.z; dc[4*u+3]=b.w;
    }
  }
  __syncthreads();
  #pragma unroll 1
  for (int u = 0; u < 8; u++){
    const int gi = r0 + RMAP(ty,u);
    const float* xi = &Xr[RMAP(ty,u)*33];
    const float ni = nr[gi];
    ushort vals[8];
    #pragma unroll 1
    for (int v = 0; v < 8; v++){
      const int gj = c0 + CMAP(tx,v);
      const float* xj = &Xc[CMAP(tx,v)*33];
      float d = 0.f;
      #pragma unroll
      for (int k = 0; k < 32; k++) d += xi[k] * xj[k];
      vals[v] = f2bf(__expf(-(ni + nc[gj] - 2.f*d) * (1.f/32.f)));
    }
    ushort* pd = Mh + (size_t)gi * NN + c0 + tx*4;
    *(ushort4*)pd        = make_ushort4(vals[0], vals[1], vals[2], vals[3]);
    *(ushort4*)(pd + 64) = make_ushort4(vals[4], vals[5], vals[6], vals[7]);
  }
}

// ---------------- fp32 -> bf16 (hi only; trace GEMMs run pure bf16) ----------------
__global__ __launch_bounds__(256) void k_split(const float* __restrict__ S,
                                               ushort* __restrict__ H){
  size_t i = ((size_t)blockIdx.x * 256 + threadIdx.x) * 4;
  float4 x = *(const float4*)(S + i);
  *(ushort4*)(H + i) = make_ushort4(f2bf(x.x), f2bf(x.y), f2bf(x.z), f2bf(x.w));
}

// ---------------- MFMA bf16 GEMM + fused RBF-trace epilogue(s) + fused tr(L*A) ----
__global__ __launch_bounds__(256) void k_mfma_tr(
    const ushort* __restrict__ Ah, const ushort* __restrict__ Bh,
    int sym, int doRed, int nepi,
    const float* e0xr, const float* e0xc, const float* e0nr, const float* e0nc, int s0, int rs0,
    const float* e1xr, const float* e1xc, const float* e1nr, const float* e1nc, int s1, int rs1,
    float* __restrict__ slots){
  __shared__ __align__(16) ushort shb[24576];   // 48 KB: 3-deep staging ring / epilogue X tiles
  __shared__ float red[4];
  int bi, bj;
  if (sym){
    int p = blockIdx.x;
    p = (p & 7) * (NTRI/8) + (p >> 3);
    tri_map(p, bi, bj);
  } else {
    int id = blockIdx.y * NBLK + blockIdx.x;
    id = (id & 7) * ((NBLK*NBLK)/8) + (id >> 3);
    bi = id / NBLK; bj = id % NBLK;
  }
  const int r0 = bi * 128, c0 = bj * 128;
  const float wgt = (sym && bi != bj) ? 2.f : 1.f;
  const int t = threadIdx.x;
  const int L = t & 63, w = t >> 6;
  const int wr = w >> 1, wc = w & 1;
  const int lm = L & 15, quad = L >> 4;
  const int sch = (t & 3) * 8;

  f32x4 acc[4][4];
  #pragma unroll
  for (int i = 0; i < 4; i++)
    #pragma unroll
    for (int j = 0; j < 4; j++) acc[i][j] = (f32x4){0.f, 0.f, 0.f, 0.f};

  PIPE_MAIN_LOOP();
  __syncthreads();   // full drain; staging ring now dead -> reuse for epilogue X tiles

  // -------- fused RBF-trace epilogue(s) --------
  #pragma unroll 1
  for (int e = 0; e < nepi; e++){
    const float* xr = e ? e1xr : e0xr;
    const float* xc = e ? e1xc : e0xc;
    const float* nr = e ? e1nr : e0nr;
    const float* nc = e ? e1nc : e0nc;
    const int slot = e ? s1 : s0;
    const int rslot = e ? rs1 : rs0;
    ushort* Xrh = shb;          // [128][32] bf16 hi
    ushort* Xrl = shb + 4096;   // lo
    ushort* Xch = shb + 8192;
    ushort* Xcl = shb + 12288;
    {
      const int lr = t >> 1, lh = (t & 1) * 16;
      const float* pr = xr + (size_t)(r0 + lr) * DD + lh;
      const float* pc = xc + (size_t)(c0 + lr) * DD + lh;
      ushort* drh = Xrh + lr*32 + lh;  ushort* drl = Xrl + lr*32 + lh;
      ushort* dch = Xch + lr*32 + lh;  ushort* dcl = Xcl + lr*32 + lh;
      #pragma unroll
      for (int u = 0; u < 4; u++){
        float4 a = ((const float4*)pr)[u];
        ushort h0 = f2bf(a.x), h1 = f2bf(a.y), h2 = f2bf(a.z), h3 = f2bf(a.w);
        ((ushort4*)drh)[u] = make_ushort4(h0, h1, h2, h3);
        ((ushort4*)drl)[u] = make_ushort4(f2bf(a.x - bf2f(h0)), f2bf(a.y - bf2f(h1)),
                                          f2bf(a.z - bf2f(h2)), f2bf(a.w - bf2f(h3)));
        float4 b = ((const float4*)pc)[u];
        ushort g0 = f2bf(b.x), g1 = f2bf(b.y), g2 = f2bf(b.z), g3 = f2bf(b.w);
        ((ushort4*)dch)[u] = make_ushort4(g0, g1, g2, g3);
        ((ushort4*)dcl)[u] = make_ushort4(f2bf(b.x - bf2f(g0)), f2bf(b.y - bf2f(g1)),
                                          f2bf(b.z - bf2f(g2)), f2bf(b.w - bf2f(g3)));
      }
    }
    __syncthreads();
    float s = 0.f, s2 = 0.f;
    #pragma unroll 1
    for (int i = 0; i < 4; i++){
      const int ao = (wr*64 + i*16 + lm)*32 + quad*8;
      const bf16x8 ahh = *(const bf16x8*)&Xrh[ao];
      const bf16x8 ahl = *(const bf16x8*)&Xrl[ao];
      f32x4 dj[4];
      #pragma unroll
      for (int j = 0; j < 4; j++){
        const int bo = (wc*64 + j*16 + lm)*32 + quad*8;
        bf16x8 bhh = *(const bf16x8*)&Xch[bo];
        bf16x8 bhl = *(const bf16x8*)&Xcl[bo];
        f32x4 dd = (f32x4){0.f, 0.f, 0.f, 0.f};
        dd = __builtin_amdgcn_mfma_f32_16x16x32_bf16(ahh, bhh, dd, 0, 0, 0);
        dd = __builtin_amdgcn_mfma_f32_16x16x32_bf16(ahl, bhh, dd, 0, 0, 0);
        dd = __builtin_amdgcn_mfma_f32_16x16x32_bf16(ahh, bhl, dd, 0, 0, 0);
        dj[j] = dd;
      }
      #pragma unroll
      for (int rg = 0; rg < 4; rg++){
        const int rl = wr*64 + i*16 + quad*4 + rg;
        const float ni = nr[r0 + rl];
        #pragma unroll
        for (int j = 0; j < 4; j++){
          const int cl = wc*64 + j*16 + lm;
          const float Lval = __expf(-(ni + nc[c0 + cl] - 2.f*dj[j][rg]) * (1.f/32.f));
          s += acc[i][j][rg] * Lval;
          if (doRed) s2 += bf2f(Ah[(size_t)(r0 + rl) * NN + c0 + cl]) * Lval;
        }
      }
    }
    block_atomic_add(s * wgt, red, slots + slot);
    if (doRed) block_atomic_add(s2 * wgt, red, slots + rslot);
    __syncthreads();
  }
}

// ---------------- plain MFMA bf16 GEMM, bf16 store (V = B * QP^T-row layout) ----------
__global__ __launch_bounds__(256) void k_mfma_gemm(
    const ushort* __restrict__ Ah, const ushort* __restrict__ Bh,
    ushort* __restrict__ Dh){
  __shared__ __align__(16) ushort shb[24576];   // 48 KB 3-deep staging ring
  int id = blockIdx.y * NBLK + blockIdx.x;
  id = (id & 7) * ((NBLK*NBLK)/8) + (id >> 3);
  const int r0 = (id / NBLK) * 128, c0 = (id % NBLK) * 128;
  const int t = threadIdx.x;
  const int L = t & 63, w = t >> 6;
  const int wr = w >> 1, wc = w & 1;
  const int lm = L & 15, quad = L >> 4;
  const int sch = (t & 3) * 8;
  f32x4 acc[4][4];
  #pragma unroll
  for (int i = 0; i < 4; i++)
    #pragma unroll
    for (int j = 0; j < 4; j++) acc[i][j] = (f32x4){0.f, 0.f, 0.f, 0.f};
  PIPE_MAIN_LOOP();
  #pragma unroll
  for (int i = 0; i < 4; i++)
    #pragma unroll
    for (int j = 0; j < 4; j++)
      #pragma unroll
      for (int rg = 0; rg < 4; rg++){
        const int row = wr*64 + i*16 + quad*4 + rg;
        const int col = wc*64 + j*16 + lm;
        Dh[(size_t)(r0 + row) * NN + c0 + col] = f2bf(acc[i][j][rg]);
      }
}

// ---------------- GJ diag-block inverse (standalone, kb=0 bootstrap only) ------------
// P buffers are parity-double-buffered: par = kb & 1, index (par*2 + mat).
__global__ __launch_bounds__(512) void k_gj_diag(
    float* __restrict__ M0, float* __restrict__ M1,
    float* __restrict__ Pbuf, ushort* __restrict__ Pth, ushort* __restrict__ Ptl,
    int kb){
  __shared__ float Ps[128 * 132];
  __shared__ __align__(16) float rowbufD[2][144];
  __shared__ float colbufD[2][128];
  const int mat = blockIdx.y;
  const int par = kb & 1;
  float* M = mat ? M1 : M0;
  float* P = Pbuf + (size_t)(par*2 + mat) * NB * NB;
  ushort* Ph = Pth + (size_t)(par*2 + mat) * NB * NB;
  ushort* Pl = Ptl + (size_t)(par*2 + mat) * NB * NB;
  const int k0 = kb * NB;
  const int t = threadIdx.x;
  const int g = t >> 7, r = t & 127;
  float reg[32];
  {
    const float* mrow = M + (size_t)(k0 + r) * NN + k0 + g * 32;
    #pragma unroll
    for (int u = 0; u < 8; u++){
      float4 v = ((const float4*)mrow)[u];
      reg[4*u+0]=v.x; reg[4*u+1]=v.y; reg[4*u+2]=v.z; reg[4*u+3]=v.w;
    }
  }
  if (r == 0){
    #pragma unroll
    for (int u = 0; u < 8; u++)
      *(float4*)&rowbufD[0][g*36 + 4*u] =
          make_float4(reg[4*u], reg[4*u+1], reg[4*u+2], reg[4*u+3]);
  }
  if (g == 0) colbufD[0][r] = reg[0];
  __syncthreads();
  #pragma unroll 1
  for (int jj = 0; jj < NB; jj++){
    const int pj = jj & 1, pn = pj ^ 1;
    const float pv = 1.0f / rowbufD[pj][(jj>>5)*36 + (jj&31)];
    const int gp = jj >> 5, gq = (jj+1) >> 5;
    const int ep = jj & 31, eq = (jj+1) & 31;
    if (r == jj){
      if (g == gp){
        #pragma unroll
        for (int e = 0; e < 32; e++) reg[e] = (e == ep) ? pv : reg[e] * pv;
      } else {
        #pragma unroll
        for (int e = 0; e < 32; e++) reg[e] = reg[e] * pv;
      }
      if (g == gq){
        #pragma unroll
        for (int e = 0; e < 32; e++) if (e == eq) colbufD[pn][r] = reg[e];
      }
    } else {
      const float f = colbufD[pj][r] * pv;
      if (g == gp){
        #pragma unroll
        for (int u = 0; u < 8; u++){
          float4 rv = *(const float4*)&rowbufD[pj][g*36 + 4*u];
          reg[4*u+0] = (4*u+0 == ep) ? (-f) : fmaf(-f, rv.x, reg[4*u+0]);
          reg[4*u+1] = (4*u+1 == ep) ? (-f) : fmaf(-f, rv.y, reg[4*u+1]);
          reg[4*u+2] = (4*u+2 == ep) ? (-f) : fmaf(-f, rv.z, reg[4*u+2]);
          reg[4*u+3] = (4*u+3 == ep) ? (-f) : fmaf(-f, rv.w, reg[4*u+3]);
        }
      } else {
        #pragma unroll
        for (int u = 0; u < 8; u++){
          float4 rv = *(const float4*)&rowbufD[pj][g*36 + 4*u];
          reg[4*u+0] = fmaf(-f, rv.x, reg[4*u+0]);
          reg[4*u+1] = fmaf(-f, rv.y, reg[4*u+1]);
          reg[4*u+2] = fmaf(-f, rv.z, reg[4*u+2]);
          reg[4*u+3] = fmaf(-f, rv.w, reg[4*u+3]);
        }
      }
      if (g == gq){
        #pragma unroll
        for (int e = 0; e < 32; e++) if (e == eq) colbufD[pn][r] = reg[e];
      }
      if (r == jj + 1){
        #pragma unroll
        for (int u = 0; u < 8; u++)
          *(float4*)&rowbufD[pn][g*36 + 4*u] =
              make_float4(reg[4*u], reg[4*u+1], reg[4*u+2], reg[4*u+3]);
      }
    }
    __syncthreads();
  }
  #pragma unroll
  for (int u = 0; u < 8; u++)
    *(float4*)&Ps[r*132 + g*32 + 4*u] =
        make_float4(reg[4*u], reg[4*u+1], reg[4*u+2], reg[4*u+3]);
  __syncthreads();
  {
    const int r2 = t >> 2, q2 = t & 3;
    #pragma unroll
    for (int e = 0; e < 8; e++)
      *(float4*)&P[r2*NB + q2*32 + 4*e] = *(const float4*)&Ps[r2*132 + q2*32 + 4*e];
  }
  {
    const int c = t >> 2, rbp = (t & 3) * 32;
    #pragma unroll
    for (int q4 = 0; q4 < 8; q4++){
      ushort h4[4], l4[4];
      #pragma unroll
      for (int e = 0; e < 4; e++){
        float v = Ps[(rbp + q4*4 + e)*132 + c];
        ushort h = f2bf(v);
        h4[e] = h; l4[e] = f2bf(v - bf2f(h));
      }
      *(ushort4*)(Ph + (size_t)c * NB + rbp + q4*4) = make_ushort4(h4[0], h4[1], h4[2], h4[3]);
      *(ushort4*)(Pl + (size_t)c * NB + rbp + q4*4) = make_ushort4(l4[0], l4[1], l4[2], l4[3]);
    }
  }
}

// ---------------- GJ panel: T = P * M[krow, jtile] (grid 32 jtiles x 2 mats) --------
__global__ __launch_bounds__(256) void k_gj_panel(
    float* __restrict__ M0, float* __restrict__ M1,
    const float* __restrict__ Pbuf,
    float* __restrict__ Tf, ushort* __restrict__ Tth, ushort* __restrict__ Ttl,
    ushort* __restrict__ Chh, ushort* __restrict__ Chl, int kb){
  __shared__ float Ps[128 * 132];
  __shared__ float Bs[16 * 132];
  const int mat = blockIdx.y;
  const int par = kb & 1;
  float* M = mat ? M1 : M0;
  const float* P = Pbuf + (size_t)(par*2 + mat) * NB * NB;
  float* Tfm = Tf + (size_t)mat * NB * NN;
  ushort* Th = Tth + (size_t)mat * NN * NB;
  ushort* Tl = Ttl + (size_t)mat * NN * NB;
  ushort* Ch = Chh + (size_t)mat * NN * NB;
  ushort* Cl = Chl + (size_t)mat * NN * NB;
  const int k0 = kb * NB;
  const int j0 = blockIdx.x * 128;
  const int t = threadIdx.x;
  const int row = t >> 1, hc = (t & 1) * 64;
  // stage P (L2-hot) into Ps
  {
    const float* src = P + (size_t)row * NB + hc;
    float* dst = &Ps[row*132 + hc];
    #pragma unroll
    for (int u = 0; u < 16; u++) ((float4*)dst)[u] = ((const float4*)src)[u];
  }
  // C split copy of M[:, kcol] panel (rows j0..j0+127) - pre-update values
  {
    const float* src = M + (size_t)(j0 + row) * NN + k0 + hc;
    ushort* dh = Ch + (size_t)(j0 + row) * NB + hc;
    ushort* dl = Cl + (size_t)(j0 + row) * NB + hc;
    #pragma unroll
    for (int u = 0; u < 16; u++){
      float4 v = ((const float4*)src)[u];
      ushort h0 = f2bf(v.x), h1 = f2bf(v.y), h2 = f2bf(v.z), h3 = f2bf(v.w);
      ((ushort4*)dh)[u] = make_ushort4(h0, h1, h2, h3);
      ((ushort4*)dl)[u] = make_ushort4(f2bf(v.x - bf2f(h0)), f2bf(v.y - bf2f(h1)),
                                       f2bf(v.z - bf2f(h2)), f2bf(v.w - bf2f(h3)));
    }
  }
  __syncthreads();
  const int tx = t & 15, ty = t >> 4;
  float acc[8][8];
  #pragma unroll
  for (int u = 0; u < 8; u++)
    #pragma unroll
    for (int v = 0; v < 8; v++) acc[u][v] = 0.f;
  for (int ks = 0; ks < NB; ks += 16){
    {
      const int kkl = t >> 4, c8 = (t & 15) * 8;
      const float* pb = M + (size_t)(k0 + ks + kkl) * NN + j0 + c8;
      float4 b0 = ((const float4*)pb)[0];
      float4 b1 = ((const float4*)pb)[1];
      *(float4*)&Bs[kkl*132 + c8]     = b0;
      *(float4*)&Bs[kkl*132 + c8 + 4] = b1;
    }
    __syncthreads();
    #pragma unroll
    for (int kk = 0; kk < 16; kk++){
      float a[8], b[8];
      #pragma unroll
      for (int u = 0; u < 8; u++) a[u] = Ps[RMAP(ty,u)*132 + ks + kk];
      float4 b0 = *(const float4*)&Bs[kk*132 + tx*4];
      float4 b1 = *(const float4*)&Bs[kk*132 + tx*4 + 64];
      b[0]=b0.x; b[1]=b0.y; b[2]=b0.z; b[3]=b0.w;
      b[4]=b1.x; b[5]=b1.y; b[6]=b1.z; b[7]=b1.w;
      #pragma unroll
      for (int u = 0; u < 8; u++)
        #pragma unroll
        for (int v = 0; v < 8; v++) acc[u][v] += a[u] * b[v];
    }
    __syncthreads();
  }
  // write T fp32 (coalesced)
  #pragma unroll
  for (int u = 0; u < 8; u++){
    const int rr = RMAP(ty,u);
    float* pd = Tfm + (size_t)rr * NN + j0 + tx*4;
    *(float4*)pd        = make_float4(acc[u][0], acc[u][1], acc[u][2], acc[u][3]);
    *(float4*)(pd + 64) = make_float4(acc[u][4], acc[u][5], acc[u][6], acc[u][7]);
  }
  // transposed T bf16-split via LDS (Ps aliased; dead after GEMM)
  ushort* Tls_h = (ushort*)Ps;
  ushort* Tls_l = Tls_h + 128*132;
  __syncthreads();
  #pragma unroll
  for (int u = 0; u < 8; u++){
    const int rr = RMAP(ty,u);
    #pragma unroll
    for (int v = 0; v < 8; v++){
      const int ccl = CMAP(tx,v);
      float val = acc[u][v];
      ushort h = f2bf(val);
      Tls_h[ccl*132 + rr] = h;
      Tls_l[ccl*132 + rr] = f2bf(val - bf2f(h));
    }
  }
  __syncthreads();
  {
    const int ccl = t >> 1, rb = (t & 1) * 64;
    ushort* th = Th + (size_t)(j0 + ccl) * NB + rb;
    ushort* tl = Tl + (size_t)(j0 + ccl) * NB + rb;
    #pragma unroll
    for (int q4 = 0; q4 < 16; q4++){
      *(ushort4*)(th + q4*4) = *(const ushort4*)(Tls_h + ccl*132 + rb + q4*4);
      *(ushort4*)(tl + q4*4) = *(const ushort4*)(Tls_l + ccl*132 + rb + q4*4);
    }
  }
}

// Trailing update (half-grid by row parity) + skewed rider diag.
// hpar selects rows: ib = 2*blockIdx.y + hpar. U1 (hpar=(kb+1)&1) updates tile
// (kb+1,kb+1); U2 (hpar=kb&1) carries a RIDER block (blockIdx.x==32, y==0) that
// inverts the U1-finalized tile (kb+1,kb+1) CONCURRENTLY with U2's 1024 fat MFMA
// blocks — starts at dispatch time 0 at boosted clocks, hiding the serial latency.
__global__ __launch_bounds__(256) void k_gj_update3(float* __restrict__ M0, float* __restrict__ M1,
    float* __restrict__ Pbuf, ushort* __restrict__ Pth, ushort* __restrict__ Ptl,
    const float* __restrict__ Tf,
    const ushort* __restrict__ Tth, const ushort* __restrict__ Ttl,
    const ushort* __restrict__ Chh, const ushort* __restrict__ Chl,
    int kb, int hpar, int doRider){
  __shared__ __align__(16) float shchunk[64 * 132];   // 33.8 KB; staging/transpose/rider-writeout
  __shared__ __align__(16) float rowD[2][160];        // rider pivot row
  __shared__ float colD[2][128];                      // rider pivot col
  const int mat = blockIdx.z;
  const int par = kb & 1;
  float* M = mat ? M1 : M0;
  const int k0 = kb * NB;
  const int t = threadIdx.x;
  // ================= rider: diag inverse of tile (kb+1,kb+1) =================
  if (blockIdx.x == 32){
    if (blockIdx.y != 0 || !doRider) return;
    const int k0n = (kb + 1) * NB;
    const int r = t & 127, gs = t >> 7;   // gs: 64-col strip, wave-uniform
    float reg[64];
    {
      const float* mrow = M + (size_t)(k0n + r) * NN + k0n + gs * 64;
      #pragma unroll
      for (int u = 0; u < 16; u++){
        float4 v = ((const float4*)mrow)[u];
        reg[4*u+0]=v.x; reg[4*u+1]=v.y; reg[4*u+2]=v.z; reg[4*u+3]=v.w;
      }
    }
    if (r == 0){
      #pragma unroll
      for (int u = 0; u < 16; u++)
        *(float4*)&rowD[0][gs*80 + 4*u] =
            make_float4(reg[4*u], reg[4*u+1], reg[4*u+2], reg[4*u+3]);
    }
    if (gs == 0) colD[0][r] = reg[0];
    __syncthreads();
    #pragma unroll 1
    for (int jj = 0; jj < NB; jj++){
      const int pj = jj & 1, pn = pj ^ 1;
      const float pv = 1.0f / rowD[pj][(jj>>6)*80 + (jj&63)];
      const int gp = jj >> 6, gq = (jj+1) >> 6;
      const int ep = jj & 63, eq = (jj+1) & 63;
      if (r == jj){
        if (gs == gp){
          #pragma unroll
          for (int e = 0; e < 64; e++) reg[e] = (e == ep) ? pv : reg[e] * pv;
        } else {
          #pragma unroll
          for (int e = 0; e < 64; e++) reg[e] = reg[e] * pv;
        }
        if (gs == gq){
          #pragma unroll
          for (int e = 0; e < 64; e++) if (e == eq) colD[pn][r] = reg[e];
        }
      } else {
        const float f = colD[pj][r] * pv;
        if (gs == gp){
          #pragma unroll
          for (int u = 0; u < 16; u++){
            float4 rv = *(const float4*)&rowD[pj][gs*80 + 4*u];
            reg[4*u+0] = (4*u+0 == ep) ? (-f) : fmaf(-f, rv.x, reg[4*u+0]);
            reg[4*u+1] = (4*u+1 == ep) ? (-f) : fmaf(-f, rv.y, reg[4*u+1]);
            reg[4*u+2] = (4*u+2 == ep) ? (-f) : fmaf(-f, rv.z, reg[4*u+2]);
            reg[4*u+3] = (4*u+3 == ep) ? (-f) : fmaf(-f, rv.w, reg[4*u+3]);
          }
        } else {
          #pragma unroll
          for (int u = 0; u < 16; u++){
            float4 rv = *(const float4*)&rowD[pj][gs*80 + 4*u];
            reg[4*u+0] = fmaf(-f, rv.x, reg[4*u+0]);
            reg[4*u+1] = fmaf(-f, rv.y, reg[4*u+1]);
            reg[4*u+2] = fmaf(-f, rv.z, reg[4*u+2]);
            reg[4*u+3] = fmaf(-f, rv.w, reg[4*u+3]);
          }
        }
        if (gs == gq){
          #pragma unroll
          for (int e = 0; e < 64; e++) if (e == eq) colD[pn][r] = reg[e];
        }
        if (r == jj + 1){
          #pragma unroll
          for (int u = 0; u < 16; u++)
            *(float4*)&rowD[pn][gs*80 + 4*u] =
                make_float4(reg[4*u], reg[4*u+1], reg[4*u+2], reg[4*u+3]);
        }
      }
      __syncthreads();
    }
    // P(kb+1) writeout at parity (kb+1)&1
    float* Pn  = Pbuf + (size_t)(((par^1)*2) + mat) * NB * NB;
    ushort* Phn = Pth + (size_t)(((par^1)*2) + mat) * NB * NB;
    ushort* Pln = Ptl + (size_t)(((par^1)*2) + mat) * NB * NB;
    #pragma unroll
    for (int u = 0; u < 16; u++)
      *(float4*)&Pn[r*NB + gs*64 + 4*u] =
          make_float4(reg[4*u], reg[4*u+1], reg[4*u+2], reg[4*u+3]);
    ushort* Xh = (ushort*)shchunk;        // [64 cols][132 rows-pad]
    ushort* Xl = Xh + 64*132;
    #pragma unroll 1
    for (int cp = 0; cp < 2; cp++){
      __syncthreads();
      if (gs == cp){
        #pragma unroll
        for (int e = 0; e < 64; e++){
          float v = reg[e]; ushort h = f2bf(v);
          Xh[e*132 + r] = h; Xl[e*132 + r] = f2bf(v - bf2f(h));
        }
      }
      __syncthreads();
      const int c = t >> 2, rb = (t & 3) * 32;
      #pragma unroll
      for (int q = 0; q < 8; q++){
        *(ushort4*)(Phn + (size_t)(cp*64 + c) * NB + rb + 4*q) =
            *(const ushort4*)&Xh[c*132 + rb + 4*q];
        *(ushort4*)(Pln + (size_t)(cp*64 + c) * NB + rb + 4*q) =
            *(const ushort4*)&Xl[c*132 + rb + 4*q];
      }
    }
    return;
  }
  // ================= regular half-grid update =================
  const float* P = Pbuf + (size_t)(par*2 + mat) * NB * NB;
  const ushort* Ph = Pth + (size_t)(par*2 + mat) * NB * NB;
  const ushort* Pl = Ptl + (size_t)(par*2 + mat) * NB * NB;
  const float* Tfm = Tf + (size_t)mat * NB * NN;
  const ushort* Th = Tth + (size_t)mat * NN * NB;
  const ushort* Tl = Ttl + (size_t)mat * NN * NB;
  const ushort* Ch = Chh + (size_t)mat * NN * NB;
  const ushort* Cl = Chl + (size_t)mat * NN * NB;
  const int jb = blockIdx.x, ib = 2*blockIdx.y + hpar;
  const int i0 = ib * NB, j0 = jb * NB;
  ushort* tAh = (ushort*)shchunk;
  ushort* tAl = tAh + 4096;
  ushort* tBh = tAl + 4096;
  ushort* tBl = tBh + 4096;
  if (ib == kb){
    const int row = t >> 1, half = (t & 1) * 64;
    float* dst = M + (size_t)(k0 + row) * NN + j0 + half;
    if (jb == kb){
      const float* src = P + (size_t)row * NB + half;
      #pragma unroll
      for (int u = 0; u < 16; u++) ((float4*)dst)[u] = ((const float4*)src)[u];
    } else {
      const float* src = Tfm + (size_t)row * NN + j0 + half;
      #pragma unroll
      for (int u = 0; u < 16; u++) ((float4*)dst)[u] = ((const float4*)src)[u];
    }
    return;
  }
  const int L = t & 63, w = t >> 6;
  const int wr = w >> 1, wc = w & 1;
  const int lm = L & 15, quad = L >> 4;
  const int sch = (t & 3) * 8;
  const ushort* Bh = (jb == kb) ? Ph : (Th + (size_t)j0 * NB);
  const ushort* Bl = (jb == kb) ? Pl : (Tl + (size_t)j0 * NB);
  const ushort* Ahp = Ch + (size_t)i0 * NB;
  const ushort* Alp = Cl + (size_t)i0 * NB;
  f32x4 acc[4][4];
  #pragma unroll
  for (int i = 0; i < 4; i++)
    #pragma unroll
    for (int j = 0; j < 4; j++) acc[i][j] = (f32x4){0.f, 0.f, 0.f, 0.f};
  for (int ks = 0; ks < NB; ks += 32){
    #pragma unroll
    for (int p = 0; p < 2; p++){
      const int row = p*64 + (t >> 2);
      const size_t ga = (size_t)row * NB + ks + sch;
      const int lo = row*32 + sch;
      stage16(Ahp + ga, tAh + lo);
      stage16(Alp + ga, tAl + lo);
      stage16(Bh + ga, tBh + lo);
      stage16(Bl + ga, tBl + lo);
    }
    __syncthreads();
    bf16x8 ah[4], al[4], bh[4], bl[4];
    #pragma unroll
    for (int i = 0; i < 4; i++){
      const int ao = (wr*64 + i*16 + lm)*32 + quad*8;
      const int bo = (wc*64 + i*16 + lm)*32 + quad*8;
      ah[i] = *(const bf16x8*)&tAh[ao];
      al[i] = *(const bf16x8*)&tAl[ao];
      bh[i] = *(const bf16x8*)&tBh[bo];
      bl[i] = *(const bf16x8*)&tBl[bo];
    }
    #pragma unroll
    for (int i = 0; i < 4; i++)
      #pragma unroll
      for (int j = 0; j < 4; j++){
        acc[i][j] = __builtin_amdgcn_mfma_f32_16x16x32_bf16(ah[i], bh[j], acc[i][j], 0, 0, 0);
        acc[i][j] = __builtin_amdgcn_mfma_f32_16x16x32_bf16(ah[i], bl[j], acc[i][j], 0, 0, 0);
        acc[i][j] = __builtin_amdgcn_mfma_f32_16x16x32_bf16(al[i], bh[j], acc[i][j], 0, 0, 0);
      }
    __syncthreads();
  }
  // chunked transpose: 2 passes of 64 rows, coalesced float4 RMW
  const int rloc = t >> 2, cg2 = (t & 3) * 4;
  const int jc0 = (jb == kb) ? k0 : j0;
  #pragma unroll 1
  for (int hp = 0; hp < 2; hp++){
    if (wr == hp){
      #pragma unroll
      for (int i = 0; i < 4; i++)
        #pragma unroll
        for (int j = 0; j < 4; j++)
          #pragma unroll
          for (int rg = 0; rg < 4; rg++){
            const int row = i*16 + quad*4 + rg;
            const int col = wc*64 + j*16 + lm;
            shchunk[row*132 + col] = acc[i][j][rg];
          }
    }
    __syncthreads();
    float* pm = M + (size_t)(i0 + hp*64 + rloc) * NN + jc0;
    if (jb == kb){
      #pragma unroll
      for (int c = 0; c < 8; c++){
        const int col = cg2 + 16*c;
        float4 v = *(float4*)&shchunk[rloc*132 + col];
        *(float4*)(pm + col) = make_float4(-v.x, -v.y, -v.z, -v.w);
      }
    } else {
      #pragma unroll
      for (int c = 0; c < 8; c++){
        const int col = cg2 + 16*c;
        float4 v = *(float4*)&shchunk[rloc*132 + col];
        float4 m = *(float4*)(pm + col);
        m.x -= v.x; m.y -= v.y; m.z -= v.z; m.w -= v.w;
        *(float4*)(pm + col) = m;
      }
    }
    __syncthreads();
  }
}

// ---------------- final combine ----------------
__global__ void k_combine(const float* __restrict__ slots, float* __restrict__ out){
  if (threadIdx.x == 0 && blockIdx.x == 0){
    const double invN2 = 1.0 / ((double)NN * (double)NN);
    double term1 = ((double)slots[0] + (double)slots[1] - 2.0 * (double)slots[2]) * invN2;
    double pairs = 0.0;
    for (int p = 0; p < 3; p++){
      const float* s = slots + 4 + 5 * p;
      pairs += ((double)s[0] - 0.2 * (double)s[1] + (double)s[2] - 0.2 * (double)s[3] - 2.0 * (double)s[4]);
    }
    out[0] = (float)(1.0 * term1 + 500.0 * pairs * invN2);
    out[1] = (float)((double)slots[3] / (2.0 * (double)NN));
  }
}

// ---------------- host ----------------
extern "C" void kernel_launch(void* const* d_in, const int* in_sizes, int n_in,
                              void* d_out, int out_size, void* d_ws, size_t ws_size,
                              hipStream_t stream){
  const float* x    = (const float*)d_in[0];
  const float* z    = (const float*)d_in[1];
  const float* zz   = (const float*)d_in[2];
  const float* xx   = (const float*)d_in[3];
  const float* stdn = (const float*)d_in[4];
  float* out = (float*)d_out;
  float* ws  = (float*)d_ws;

  const size_t NN2 = (size_t)NN * NN;
  float* R0 = ws;
  float* R1 = R0 + NN2;
  float* R2 = R1 + NN2;
  float* PanelF = R2 + NN2;
  ushort* Tth = (ushort*)PanelF;                       // 2 MB
  ushort* Ttl = Tth + 2 * (size_t)NB * NN;
  ushort* Chh = Ttl + 2 * (size_t)NB * NN;
  ushort* Chl = Chh + 2 * (size_t)NB * NN;             // panels total 8 MB
  float* Tf   = (float*)(Chl + 2 * (size_t)NB * NN);   // 4 MB fp32 T (2 mats)
  float* Pb   = Tf + 2 * (size_t)NB * NN;              // fp32 P (2 parities x 2 mats)
  ushort* Pth = (ushort*)(Pb + 4 * (size_t)NB * NB);
  ushort* Ptl = Pth + 4 * (size_t)NB * NB;
  float* slots= (float*)(Ptl + 4 * (size_t)NB * NB);
  float* stdsq= slots + 32;
  float* zrs  = stdsq + NN;
  float* nzz  = zrs + (size_t)NN * NV;
  float* nz8  = nzz + (size_t)NV * NN;
  float* nrmz = nz8 + (size_t)NV * NN;

  ushort* R0h = (ushort*)R0;   // B hi (bf16)
  ushort* R2h = (ushort*)R2;   // A hi (bf16)
  ushort* Vh  = (ushort*)R1;   // V hi (bf16, lower half of R1)
  ushort* QPh = Vh + NN2;      // Kqp bf16 (upper half of R1)

  dim3 g32(NBLK, NBLK);

  k_zero<<<1, 64, 0, stream>>>(slots, 32);
  k_norms<<<(NN * NV) / 256, 256, 0, stream>>>(z, zz, stdn, stdsq, zrs, nzz, nz8);
  k_rownorm<<<NN / 256, 256, 0, stream>>>(nz8, nrmz);
  k_nll<<<1024, 256, 0, stream>>>(x, xx, slots);
  k_sqq<<<NTRI, 256, 0, stream>>>(z, nrmz, slots);
  k_spp_sqp<<<g32, 256, 0, stream>>>(stdn, stdsq, zrs, nrmz, slots);

  const float* zz0 = zz;            const float* z0 = z;
  const float* zz1 = zz + VD;       const float* z1 = z + VD;
  const float* nzz0 = nzz;          const float* nz0 = nz8;
  const float* nzz1 = nzz + NN;     const float* nz1 = nz8 + NN;

  for (int b = 1; b <= 2; b++){
    const float* zzb = zz + b*VD;  const float* nzzb = nzz + (size_t)b*NN;
    const float* zb  = z + b*VD;   const float* nzb  = nz8 + (size_t)b*NN;
    k_rbf<<<g32, 256, 0, stream>>>(zzb, zzb, nzzb, nzzb, 0.2f, R0);
    k_rbf<<<g32, 256, 0, stream>>>(zb,  zb,  nzb,  nzb,  0.2f, R1);
    // ---- GJ chain: bootstrap diag(0); per kb: panel -> U1 (rows parity kb+1,
    //      incl. pivot tile) -> U2 (rows parity kb + skewed rider diag(kb+1)) ----
    k_gj_diag<<<dim3(1, 2), 512, 0, stream>>>(R0, R1, Pb, Pth, Ptl, 0);
    for (int kb = 0; kb < NBLK; kb++){
      k_gj_panel<<<dim3(NBLK, 2), 256, 0, stream>>>(R0, R1, Pb, Tf, Tth, Ttl,
                                                    Chh, Chl, kb);
      k_gj_update3<<<dim3(NBLK, NBLK/2, 2), 256, 0, stream>>>(
          R0, R1, Pb, Pth, Ptl, Tf, Tth, Ttl, Chh, Chl, kb, (kb+1)&1, 0);
      k_gj_update3<<<dim3(NBLK+1, NBLK/2, 2), 256, 0, stream>>>(
          R0, R1, Pb, Pth, Ptl, Tf, Tth, Ttl, Chh, Chl, kb, kb&1,
          (kb+1 < NBLK) ? 1 : 0);
    }
    // bf16 casts: A -> R2h, B -> R0h (B fp32 in R1 dead after)
    k_split<<<16384, 256, 0, stream>>>(R0, R2h);
    k_split<<<16384, 256, 0, stream>>>(R1, R0h);
    // Kqp bf16 precompute: QP[n][l] = k(zz_n, z_l), into upper half of R1
    k_rbf16<<<g32, 256, 0, stream>>>(zzb, zb, nzzb, nzb, QPh);
    // V = B * QP^T (plain bf16 GEMM); dest Vh (lower half of R1)
    k_mfma_gemm<<<g32, 256, 0, stream>>>(R0h, QPh, Vh);
    // trace GEMMs (pure bf16) with fused tr(L*A) reduction
    if (b == 1){
      k_mfma_tr<<<NTRI, 256, 0, stream>>>(R2h, R2h, 1, 1, 1,
                                          zz0, zz0, nzz0, nzz0, 5, 4,
                                          nullptr, nullptr, nullptr, nullptr, 0, 0, slots);
      k_mfma_tr<<<NTRI, 256, 0, stream>>>(R0h, R0h, 1, 1, 1,
                                          z0, z0, nz0, nz0, 7, 6,
                                          nullptr, nullptr, nullptr, nullptr, 0, 0, slots);
      k_mfma_tr<<<g32, 256, 0, stream>>>(R2h, Vh, 0, 0, 1,
                                         zz0, z0, nzz0, nz0, 8, 0,
                                         nullptr, nullptr, nullptr, nullptr, 0, 0, slots);
    } else {
      k_mfma_tr<<<NTRI, 256, 0, stream>>>(R2h, R2h, 1, 1, 2,
                                          zz1, zz1, nzz1, nzz1, 10, 9,
                                          zz0, zz0, nzz0, nzz0, 15, 14, slots);
      k_mfma_tr<<<NTRI, 256, 0, stream>>>(R0h, R0h, 1, 1, 2,
                                          z1, z1, nz1, nz1, 12, 11,
                                          z0, z0, nz0, nz0, 17, 16, slots);
      k_mfma_tr<<<g32, 256, 0, stream>>>(R2h, Vh, 0, 0, 2,
                                         zz1, z1, nzz1, nz1, 13, 0,
                                         zz0, z0, nzz0, nz0, 18, 0, slots);
    }
  }
  k_combine<<<1, 1, 0, stream>>>(slots, out);
}

// Round 9
// 15088.232 us; speedup vs baseline: 3.1875x; 3.1875x over previous
//
#include <hip/hip_runtime.h>
#include <math.h>

// Problem constants (fixed by setup_inputs)
#define NN 4096      // N samples
#define DD 256       // flat endo dim (8 vars * 32)
#define NV 8         // vars
#define VD 32        // per-var dim
#define NB 128       // GJ block size
#define NBLK (NN/NB) // 32
#define NTRI (NBLK*(NBLK+1)/2)  // 528

// fp32-GEMM output ownership mapping (bank-conflict-free)
#define RMAP(ty,u) ((ty)*4 + (((u)>>2)<<6) + ((u)&3))
#define CMAP(tx,v) ((tx)*4 + (((v)>>2)<<6) + ((v)&3))

typedef __attribute__((ext_vector_type(8))) short bf16x8;
typedef __attribute__((ext_vector_type(4))) float f32x4;

#define AS1(p) ((const __attribute__((address_space(1))) void*)(p))
#define AS3(p) ((__attribute__((address_space(3))) void*)(p))

__device__ __forceinline__ void stage16(const ushort* g, ushort* l){
  __builtin_amdgcn_global_load_lds(AS1(g), AS3(l), 16, 0, 0);
}

__device__ __forceinline__ ushort f2bf(float x){
  uint u = __float_as_uint(x);
  u += 0x7FFFu + ((u >> 16) & 1u);
  return (ushort)(u >> 16);
}
__device__ __forceinline__ float bf2f(ushort h){ return __uint_as_float(((uint)h) << 16); }

// triangular block map: p -> (bi >= bj)
__device__ __forceinline__ void tri_map(int p, int& bi, int& bj){
  int b = (int)((sqrtf(8.0f * (float)p + 1.0f) - 1.0f) * 0.5f);
  while ((b + 1) * (b + 2) / 2 <= p) b++;
  while (b * (b + 1) / 2 > p) b--;
  bi = b; bj = p - b * (b + 1) / 2;
}

// ---------------- helpers ----------------
__device__ __forceinline__ void block_atomic_add(float v, float* red, float* dst){
  #pragma unroll
  for (int off = 32; off > 0; off >>= 1) v += __shfl_down(v, off, 64);
  const int lane = threadIdx.x & 63;
  const int w = threadIdx.x >> 6;
  if (lane == 0) red[w] = v;
  __syncthreads();
  if (threadIdx.x == 0) atomicAdd(dst, red[0] + red[1] + red[2] + red[3]);
  __syncthreads();
}

// shared staging macros for the bf16 MFMA GEMM main loops
#define STAGE_AB(tAp, tBp, kk) do { \
  _Pragma("unroll") \
  for (int p_ = 0; p_ < 2; p_++){ \
    const int row_ = p_*64 + (t >> 2); \
    const int lo_ = row_*32 + sch; \
    stage16(Ah + (size_t)(r0 + row_) * NN + (kk) + sch, (tAp) + lo_); \
    stage16(Bh + (size_t)(c0 + row_) * NN + (kk) + sch, (tBp) + lo_); \
  } } while(0)

#define MFMA_STEP(tAp, tBp) do { \
  bf16x8 ah_[4], bh_[4]; \
  _Pragma("unroll") \
  for (int i_ = 0; i_ < 4; i_++){ \
    ah_[i_] = *(const bf16x8*)&(tAp)[(wr*64 + i_*16 + lm)*32 + quad*8]; \
    bh_[i_] = *(const bf16x8*)&(tBp)[(wc*64 + i_*16 + lm)*32 + quad*8]; \
  } \
  _Pragma("unroll") \
  for (int i_ = 0; i_ < 4; i_++) \
    _Pragma("unroll") \
    for (int j_ = 0; j_ < 4; j_++) \
      acc[i_][j_] = __builtin_amdgcn_mfma_f32_16x16x32_bf16(ah_[i_], bh_[j_], acc[i_][j_], 0, 0, 0); \
  } while(0)

// counted-vmcnt pipelined step (T3+T4): raw barrier, NO vmcnt(0) drain in main loop.
#define PIPE_WAIT_BAR(N) do { \
  asm volatile("s_waitcnt vmcnt(" #N ")" ::: "memory"); \
  __builtin_amdgcn_s_barrier(); \
  } while(0)
#define PIPE_BAR() do { \
  asm volatile("" ::: "memory"); \
  __builtin_amdgcn_s_barrier(); \
  asm volatile("" ::: "memory"); \
  } while(0)

// Depth-3 ring main loop over NN/32 = 128 K-steps.
#define PIPE_MAIN_LOOP() do { \
  STAGE_AB(shb + 0*8192, shb + 0*8192 + 4096, 0); \
  STAGE_AB(shb + 1*8192, shb + 1*8192 + 4096, 32); \
  STAGE_AB(shb + 2*8192, shb + 2*8192 + 4096, 64); \
  int cur = 0; \
  _Pragma("unroll 1") \
  for (int step = 0; step < 125; step++){ \
    ushort* tA = shb + cur*8192; ushort* tB = tA + 4096; \
    PIPE_WAIT_BAR(8); \
    MFMA_STEP(tA, tB); \
    PIPE_BAR(); \
    STAGE_AB(tA, tB, (step+3)*32); \
    cur++; if (cur == 3) cur = 0; \
  } \
  { ushort* tA = shb + cur*8192; ushort* tB = tA + 4096; \
    PIPE_WAIT_BAR(8); MFMA_STEP(tA, tB); cur++; if (cur == 3) cur = 0; } \
  { ushort* tA = shb + cur*8192; ushort* tB = tA + 4096; \
    PIPE_WAIT_BAR(4); MFMA_STEP(tA, tB); cur++; if (cur == 3) cur = 0; } \
  { ushort* tA = shb + cur*8192; ushort* tB = tA + 4096; \
    PIPE_WAIT_BAR(0); MFMA_STEP(tA, tB); } \
  } while(0)

// ---------------- small utility kernels ----------------
__global__ void k_zero(float* p, int n){
  int i = blockIdx.x * blockDim.x + threadIdx.x;
  if (i < n) p[i] = 0.f;
}

__global__ void k_norms(const float* __restrict__ z, const float* __restrict__ zz,
                        const float* __restrict__ stdn,
                        float* __restrict__ stdsq, float* __restrict__ zrs,
                        float* __restrict__ nzz, float* __restrict__ nz8){
  int t = blockIdx.x * blockDim.x + threadIdx.x;
  if (t >= NN * NV) return;
  int i = t / NV, v = t % NV;
  const float* zp  = z  + (size_t)i * DD + v * VD;
  const float* zzp = zz + (size_t)i * DD + v * VD;
  float s1 = 0.f, s2 = 0.f, s2z = 0.f;
  #pragma unroll
  for (int k = 0; k < VD; k++){
    float a = zp[k];  s1 += a; s2 += a * a;
    float b = zzp[k]; s2z += b * b;
  }
  zrs[(size_t)i * NV + v] = s1;
  nz8[(size_t)v * NN + i] = s2;
  nzz[(size_t)v * NN + i] = s2z;
  if (v == 0){
    float s = 0.f;
    #pragma unroll
    for (int u = 0; u < NV; u++){ float a = stdn[(size_t)i * NV + u]; s += a * a; }
    stdsq[i] = s;
  }
}

__global__ void k_rownorm(const float* __restrict__ nz8, float* __restrict__ nrmz){
  int i = blockIdx.x * blockDim.x + threadIdx.x;
  if (i < NN){
    float s = 0.f;
    #pragma unroll
    for (int v = 0; v < NV; v++) s += nz8[(size_t)v * NN + i];
    nrmz[i] = s;
  }
}

__global__ __launch_bounds__(256) void k_nll(const float* __restrict__ x,
                                             const float* __restrict__ xx,
                                             float* __restrict__ slots){
  __shared__ float red[4];
  float s = 0.f;
  const int total = NN * DD;
  for (int i = (blockIdx.x * 256 + threadIdx.x) * 4; i < total; i += gridDim.x * 256 * 4){
    float4 a = *(const float4*)(x + i);
    float4 b = *(const float4*)(xx + i);
    float d0 = b.x - a.x, d1 = b.y - a.y, d2 = b.z - a.z, d3 = b.w - a.w;
    s += d0*d0 + d1*d1 + d2*d2 + d3*d3;
  }
  block_atomic_add(s, red, slots + 3);
}

// ---------------- first (exo-free) MMD term ----------------
__global__ __launch_bounds__(256) void k_sqq(const float* __restrict__ z,
                                             const float* __restrict__ nrm,
                                             float* __restrict__ slots){
  __shared__ float Xr[128 * 33];
  __shared__ float Xc[128 * 33];
  __shared__ float red[4];
  int bi, bj; tri_map(blockIdx.x, bi, bj);
  const int r0 = bi * 128, c0 = bj * 128;
  const float wgt = (bi != bj) ? 2.f : 1.f;
  const int t = threadIdx.x;
  const int tx = t & 15, ty = t >> 4;
  const int lrow = t >> 1, lh = t & 1;
  float acc[8][8];
  #pragma unroll
  for (int u = 0; u < 8; u++)
    #pragma unroll
    for (int v = 0; v < 8; v++) acc[u][v] = 0.f;
  for (int ks = 0; ks < DD; ks += 32){
    const float* pr = z + (size_t)(r0 + lrow) * DD + ks + lh * 16;
    const float* pc = z + (size_t)(c0 + lrow) * DD + ks + lh * 16;
    float* dr = &Xr[lrow * 33 + lh * 16];
    float* dc = &Xc[lrow * 33 + lh * 16];
    #pragma unroll
    for (int u = 0; u < 4; u++){
      float4 a = ((const float4*)pr)[u];
      dr[4*u+0] = a.x; dr[4*u+1] = a.y; dr[4*u+2] = a.z; dr[4*u+3] = a.w;
      float4 b = ((const float4*)pc)[u];
      dc[4*u+0] = b.x; dc[4*u+1] = b.y; dc[4*u+2] = b.z; dc[4*u+3] = b.w;
    }
    __syncthreads();
    #pragma unroll
    for (int kk = 0; kk < 32; kk++){
      float a[8], b[8];
      #pragma unroll
      for (int u = 0; u < 8; u++) a[u] = Xr[RMAP(ty,u)*33 + kk];
      #pragma unroll
      for (int v = 0; v < 8; v++) b[v] = Xc[CMAP(tx,v)*33 + kk];
      #pragma unroll
      for (int u = 0; u < 8; u++)
        #pragma unroll
        for (int v = 0; v < 8; v++) acc[u][v] += a[u] * b[v];
    }
    __syncthreads();
  }
  float s = 0.f;
  #pragma unroll 1
  for (int u = 0; u < 8; u++){
    const float ni = nrm[r0 + RMAP(ty,u)];
    #pragma unroll 1
    for (int v = 0; v < 8; v++)
      s += __expf(-(ni + nrm[c0 + CMAP(tx,v)] - 2.f * acc[u][v]) * (1.f/2048.f));
  }
  block_atomic_add(s * wgt, red, slots + 0);
}

__global__ __launch_bounds__(256) void k_spp_sqp(const float* __restrict__ stdn,
                                                 const float* __restrict__ stdsq,
                                                 const float* __restrict__ zrs,
                                                 const float* __restrict__ nrmz,
                                                 float* __restrict__ slots){
  __shared__ float sI[128*9], sJ[128*9], zI[128*9];
  __shared__ float qI[128], qJ[128], nI[128];
  __shared__ float red[4];
  const int r0 = blockIdx.y * 128, c0 = blockIdx.x * 128;
  const int t = threadIdx.x;
  if (t < 128){
    #pragma unroll
    for (int v = 0; v < 8; v++){
      sI[t*9+v] = stdn[(size_t)(r0+t)*NV + v];
      sJ[t*9+v] = stdn[(size_t)(c0+t)*NV + v];
      zI[t*9+v] = zrs[(size_t)(r0+t)*NV + v];
    }
    qI[t] = stdsq[r0+t]; qJ[t] = stdsq[c0+t]; nI[t] = nrmz[r0+t];
  }
  __syncthreads();
  const int tx = t & 15, ty = t >> 4;
  float spp = 0.f, sqp = 0.f;
  #pragma unroll 1
  for (int u = 0; u < 8; u++){
    int i = ty + 16*u;
    #pragma unroll 1
    for (int v = 0; v < 8; v++){
      int j = tx + 16*v;
      float dpp = 0.f, dqp = 0.f;
      #pragma unroll
      for (int k = 0; k < 8; k++){
        float sj = sJ[j*9+k];
        dpp += sI[i*9+k] * sj;
        dqp += zI[i*9+k] * sj;
      }
      spp += __expf(-(qI[i] + qJ[j] - 2.f*dpp) * (1.f/64.f));
      sqp += __expf(-(nI[i] + 32.f*qJ[j] - 2.f*dqp) * (1.f/2048.f));
    }
  }
  block_atomic_add(spp, red, slots + 1);
  block_atomic_add(sqp, red, slots + 2);
}

// ---------------- RBF Gram matrix build (K=32, fp32 out) ----------------
__global__ __launch_bounds__(256) void k_rbf(const float* __restrict__ Xr_,
                                             const float* __restrict__ Xc_,
                                             const float* __restrict__ nr,
                                             const float* __restrict__ nc,
                                             float lam, float* __restrict__ M){
  __shared__ float Xr[128 * 33];
  __shared__ float Xc[128 * 33];
  const int r0 = blockIdx.y * 128, c0 = blockIdx.x * 128;
  const int t = threadIdx.x;
  const int tx = t & 15, ty = t >> 4;
  const int lrow = t >> 1, lh = t & 1;
  {
    const float* pr = Xr_ + (size_t)(r0 + lrow) * DD + lh * 16;
    const float* pc = Xc_ + (size_t)(c0 + lrow) * DD + lh * 16;
    float* dr = &Xr[lrow * 33 + lh * 16];
    float* dc = &Xc[lrow * 33 + lh * 16];
    #pragma unroll
    for (int u = 0; u < 4; u++){
      float4 a = ((const float4*)pr)[u];
      dr[4*u+0]=a.x; dr[4*u+1]=a.y; dr[4*u+2]=a.z; dr[4*u+3]=a.w;
      float4 b = ((const float4*)pc)[u];
      dc[4*u+0]=b.x; dc[4*u+1]=b.y; dc[4*u+2]=b.z; dc[4*u+3]=b.w;
    }
  }
  __syncthreads();
  #pragma unroll 1
  for (int u = 0; u < 8; u++){
    const int gi = r0 + RMAP(ty,u);
    const float* xi = &Xr[RMAP(ty,u)*33];
    const float ni = nr[gi];
    float vals[8];
    #pragma unroll 1
    for (int v = 0; v < 8; v++){
      const int gj = c0 + CMAP(tx,v);
      const float* xj = &Xc[CMAP(tx,v)*33];
      float d = 0.f;
      #pragma unroll
      for (int k = 0; k < 32; k++) d += xi[k] * xj[k];
      float e = __expf(-(ni + nc[gj] - 2.f*d) * (1.f/32.f));
      if (gi == gj) e += lam;
      vals[v] = e;
    }
    float* pd = M + (size_t)gi * NN + c0 + tx*4;
    *(float4*)pd        = make_float4(vals[0], vals[1], vals[2], vals[3]);
    *(float4*)(pd + 64) = make_float4(vals[4], vals[5], vals[6], vals[7]);
  }
}

// ---------------- RBF Gram matrix build (K=32, bf16 out, no diag reg) ----------------
__global__ __launch_bounds__(256) void k_rbf16(const float* __restrict__ Xr_,
                                               const float* __restrict__ Xc_,
                                               const float* __restrict__ nr,
                                               const float* __restrict__ nc,
                                               ushort* __restrict__ Mh){
  __shared__ float Xr[128 * 33];
  __shared__ float Xc[128 * 33];
  const int r0 = blockIdx.y * 128, c0 = blockIdx.x * 128;
  const int t = threadIdx.x;
  const int tx = t & 15, ty = t >> 4;
  const int lrow = t >> 1, lh = t & 1;
  {
    const float* pr = Xr_ + (size_t)(r0 + lrow) * DD + lh * 16;
    const float* pc = Xc_ + (size_t)(c0 + lrow) * DD + lh * 16;
    float* dr = &Xr[lrow * 33 + lh * 16];
    float* dc = &Xc[lrow * 33 + lh * 16];
    #pragma unroll
    for (int u = 0; u < 4; u++){
      float4 a = ((const float4*)pr)[u];
      dr[4*u+0]=a.x; dr[4*u+1]=a.y; dr[4*u+2]=a.z; dr[4*u+3]=a.w;
      float4 b = ((const float4*)pc)[u];
      dc[4*u+0]=b.x; dc[4*u+1]=b.y; dc[4*u+2]=b.z; dc[4*u+3]=b.w;
    }
  }
  __syncthreads();
  #pragma unroll 1
  for (int u = 0; u < 8; u++){
    const int gi = r0 + RMAP(ty,u);
    const float* xi = &Xr[RMAP(ty,u)*33];
    const float ni = nr[gi];
    ushort vals[8];
    #pragma unroll 1
    for (int v = 0; v < 8; v++){
      const int gj = c0 + CMAP(tx,v);
      const float* xj = &Xc[CMAP(tx,v)*33];
      float d = 0.f;
      #pragma unroll
      for (int k = 0; k < 32; k++) d += xi[k] * xj[k];
      vals[v] = f2bf(__expf(-(ni + nc[gj] - 2.f*d) * (1.f/32.f)));
    }
    ushort* pd = Mh + (size_t)gi * NN + c0 + tx*4;
    *(ushort4*)pd        = make_ushort4(vals[0], vals[1], vals[2], vals[3]);
    *(ushort4*)(pd + 64) = make_ushort4(vals[4], vals[5], vals[6], vals[7]);
  }
}

// ---------------- fp32 -> bf16 (hi only; trace GEMMs run pure bf16) ----------------
__global__ __launch_bounds__(256) void k_split(const float* __restrict__ S,
                                               ushort* __restrict__ H){
  size_t i = ((size_t)blockIdx.x * 256 + threadIdx.x) * 4;
  float4 x = *(const float4*)(S + i);
  *(ushort4*)(H + i) = make_ushort4(f2bf(x.x), f2bf(x.y), f2bf(x.z), f2bf(x.w));
}

// ---------------- MFMA bf16 GEMM + fused RBF-trace epilogue(s) + fused tr(L*A) ----
__global__ __launch_bounds__(256) void k_mfma_tr(
    const ushort* __restrict__ Ah, const ushort* __restrict__ Bh,
    int sym, int doRed, int nepi,
    const float* e0xr, const float* e0xc, const float* e0nr, const float* e0nc, int s0, int rs0,
    const float* e1xr, const float* e1xc, const float* e1nr, const float* e1nc, int s1, int rs1,
    float* __restrict__ slots){
  __shared__ __align__(16) ushort shb[24576];   // 48 KB: 3-deep staging ring / epilogue X tiles
  __shared__ float red[4];
  int bi, bj;
  if (sym){
    int p = blockIdx.x;
    p = (p & 7) * (NTRI/8) + (p >> 3);
    tri_map(p, bi, bj);
  } else {
    int id = blockIdx.y * NBLK + blockIdx.x;
    id = (id & 7) * ((NBLK*NBLK)/8) + (id >> 3);
    bi = id / NBLK; bj = id % NBLK;
  }
  const int r0 = bi * 128, c0 = bj * 128;
  const float wgt = (sym && bi != bj) ? 2.f : 1.f;
  const int t = threadIdx.x;
  const int L = t & 63, w = t >> 6;
  const int wr = w >> 1, wc = w & 1;
  const int lm = L & 15, quad = L >> 4;
  const int sch = (t & 3) * 8;

  f32x4 acc[4][4];
  #pragma unroll
  for (int i = 0; i < 4; i++)
    #pragma unroll
    for (int j = 0; j < 4; j++) acc[i][j] = (f32x4){0.f, 0.f, 0.f, 0.f};

  PIPE_MAIN_LOOP();
  __syncthreads();   // full drain; staging ring now dead -> reuse for epilogue X tiles

  // -------- fused RBF-trace epilogue(s) --------
  #pragma unroll 1
  for (int e = 0; e < nepi; e++){
    const float* xr = e ? e1xr : e0xr;
    const float* xc = e ? e1xc : e0xc;
    const float* nr = e ? e1nr : e0nr;
    const float* nc = e ? e1nc : e0nc;
    const int slot = e ? s1 : s0;
    const int rslot = e ? rs1 : rs0;
    ushort* Xrh = shb;          // [128][32] bf16 hi
    ushort* Xrl = shb + 4096;   // lo
    ushort* Xch = shb + 8192;
    ushort* Xcl = shb + 12288;
    {
      const int lr = t >> 1, lh = (t & 1) * 16;
      const float* pr = xr + (size_t)(r0 + lr) * DD + lh;
      const float* pc = xc + (size_t)(c0 + lr) * DD + lh;
      ushort* drh = Xrh + lr*32 + lh;  ushort* drl = Xrl + lr*32 + lh;
      ushort* dch = Xch + lr*32 + lh;  ushort* dcl = Xcl + lr*32 + lh;
      #pragma unroll
      for (int u = 0; u < 4; u++){
        float4 a = ((const float4*)pr)[u];
        ushort h0 = f2bf(a.x), h1 = f2bf(a.y), h2 = f2bf(a.z), h3 = f2bf(a.w);
        ((ushort4*)drh)[u] = make_ushort4(h0, h1, h2, h3);
        ((ushort4*)drl)[u] = make_ushort4(f2bf(a.x - bf2f(h0)), f2bf(a.y - bf2f(h1)),
                                          f2bf(a.z - bf2f(h2)), f2bf(a.w - bf2f(h3)));
        float4 b = ((const float4*)pc)[u];
        ushort g0 = f2bf(b.x), g1 = f2bf(b.y), g2 = f2bf(b.z), g3 = f2bf(b.w);
        ((ushort4*)dch)[u] = make_ushort4(g0, g1, g2, g3);
        ((ushort4*)dcl)[u] = make_ushort4(f2bf(b.x - bf2f(g0)), f2bf(b.y - bf2f(g1)),
                                          f2bf(b.z - bf2f(g2)), f2bf(b.w - bf2f(g3)));
      }
    }
    __syncthreads();
    float s = 0.f, s2 = 0.f;
    #pragma unroll 1
    for (int i = 0; i < 4; i++){
      const int ao = (wr*64 + i*16 + lm)*32 + quad*8;
      const bf16x8 ahh = *(const bf16x8*)&Xrh[ao];
      const bf16x8 ahl = *(const bf16x8*)&Xrl[ao];
      f32x4 dj[4];
      #pragma unroll
      for (int j = 0; j < 4; j++){
        const int bo = (wc*64 + j*16 + lm)*32 + quad*8;
        bf16x8 bhh = *(const bf16x8*)&Xch[bo];
        bf16x8 bhl = *(const bf16x8*)&Xcl[bo];
        f32x4 dd = (f32x4){0.f, 0.f, 0.f, 0.f};
        dd = __builtin_amdgcn_mfma_f32_16x16x32_bf16(ahh, bhh, dd, 0, 0, 0);
        dd = __builtin_amdgcn_mfma_f32_16x16x32_bf16(ahl, bhh, dd, 0, 0, 0);
        dd = __builtin_amdgcn_mfma_f32_16x16x32_bf16(ahh, bhl, dd, 0, 0, 0);
        dj[j] = dd;
      }
      #pragma unroll
      for (int rg = 0; rg < 4; rg++){
        const int rl = wr*64 + i*16 + quad*4 + rg;
        const float ni = nr[r0 + rl];
        #pragma unroll
        for (int j = 0; j < 4; j++){
          const int cl = wc*64 + j*16 + lm;
          const float Lval = __expf(-(ni + nc[c0 + cl] - 2.f*dj[j][rg]) * (1.f/32.f));
          s += acc[i][j][rg] * Lval;
          if (doRed) s2 += bf2f(Ah[(size_t)(r0 + rl) * NN + c0 + cl]) * Lval;
        }
      }
    }
    block_atomic_add(s * wgt, red, slots + slot);
    if (doRed) block_atomic_add(s2 * wgt, red, slots + rslot);
    __syncthreads();
  }
}

// ---------------- plain MFMA bf16 GEMM, bf16 store (V = B * QP^T-row layout) ----------
__global__ __launch_bounds__(256) void k_mfma_gemm(
    const ushort* __restrict__ Ah, const ushort* __restrict__ Bh,
    ushort* __restrict__ Dh){
  __shared__ __align__(16) ushort shb[24576];   // 48 KB 3-deep staging ring
  int id = blockIdx.y * NBLK + blockIdx.x;
  id = (id & 7) * ((NBLK*NBLK)/8) + (id >> 3);
  const int r0 = (id / NBLK) * 128, c0 = (id % NBLK) * 128;
  const int t = threadIdx.x;
  const int L = t & 63, w = t >> 6;
  const int wr = w >> 1, wc = w & 1;
  const int lm = L & 15, quad = L >> 4;
  const int sch = (t & 3) * 8;
  f32x4 acc[4][4];
  #pragma unroll
  for (int i = 0; i < 4; i++)
    #pragma unroll
    for (int j = 0; j < 4; j++) acc[i][j] = (f32x4){0.f, 0.f, 0.f, 0.f};
  PIPE_MAIN_LOOP();
  #pragma unroll
  for (int i = 0; i < 4; i++)
    #pragma unroll
    for (int j = 0; j < 4; j++)
      #pragma unroll
      for (int rg = 0; rg < 4; rg++){
        const int row = wr*64 + i*16 + quad*4 + rg;
        const int col = wc*64 + j*16 + lm;
        Dh[(size_t)(r0 + row) * NN + c0 + col] = f2bf(acc[i][j][rg]);
      }
}

// ---------------- fused GJ diag + panel (512 threads, grid 16 x 2mats) ----------------
// Round-9: diag loop = MACRO-2 block Gauss-Jordan — two pivots per barrier epoch via
// analytic 2x2 pivot-block inverse (SPD => det>0). Halves the number of barrier-
// synchronized serial epochs (128 -> 64), which rounds 5-8 showed is the intrinsic
// cost driver (~2.4us per epoch regardless of chip load). Same FMA count, same math.
__global__ __launch_bounds__(512) void k_gj_diagpanel(
    float* __restrict__ M0, float* __restrict__ M1,
    float* __restrict__ Pbuf, ushort* __restrict__ Pth, ushort* __restrict__ Ptl,
    float* __restrict__ Tf, ushort* __restrict__ Tth, ushort* __restrict__ Ttl,
    ushort* __restrict__ Chh, ushort* __restrict__ Chl, int kb){
  __shared__ float Ps[128 * 132];
  __shared__ __align__(16) float rowbufD[2][2][144];  // [parity][pivot row 0/1][group-padded cols]
  __shared__ float colbufD[2][2][128];                // [parity][pivot col 0/1][row]
  __shared__ float Bs[2][16 * 132];
  const int mat = blockIdx.y;
  float* M = mat ? M1 : M0;
  float* P = Pbuf + (size_t)mat * NB * NB;
  ushort* Ph = Pth + (size_t)mat * NB * NB;
  ushort* Pl = Ptl + (size_t)mat * NB * NB;
  float* Tfm = Tf + (size_t)mat * NB * NN;
  ushort* Th = Tth + (size_t)mat * NN * NB;
  ushort* Tl = Ttl + (size_t)mat * NN * NB;
  ushort* Ch = Chh + (size_t)mat * NN * NB;
  ushort* Cl = Chl + (size_t)mat * NN * NB;
  const int k0 = kb * NB;
  const int t = threadIdx.x;
  // ---- macro-2 register GJ diag (thread (r=t>>2, g=t&3) owns cols [g*32, g*32+32)) ----
  {
    const int r = t >> 2, g = t & 3;
    float reg[32];
    const float* mrow = M + (size_t)(k0 + r) * NN + k0 + g*32;
    #pragma unroll
    for (int u = 0; u < 8; u++){
      float4 v = ((const float4*)mrow)[u];
      reg[4*u+0]=v.x; reg[4*u+1]=v.y; reg[4*u+2]=v.z; reg[4*u+3]=v.w;
    }
    // prologue: publish raw rows 0,1 (parity 0) and multiplier cols 0,1
    if (r < 2){
      #pragma unroll
      for (int u = 0; u < 8; u++)
        *(float4*)&rowbufD[0][r][g*36 + 4*u] =
            make_float4(reg[4*u], reg[4*u+1], reg[4*u+2], reg[4*u+3]);
    }
    if (g == 0){ colbufD[0][0][r] = reg[0]; colbufD[0][1][r] = reg[1]; }
    __syncthreads();
    #pragma unroll 1
    for (int m = 0; m < NB/2; m++){
      const int pj = m & 1, pn = pj ^ 1;
      const int pc0 = 2*m, pc1 = 2*m + 1;
      const int pg = pc0 >> 5;                 // group holding both pivot cols
      const int pe0 = pc0 & 31, pe1 = pc1 & 31;
      const float a  = rowbufD[pj][0][pg*36 + pe0];
      const float b_ = rowbufD[pj][0][pg*36 + pe1];
      const float c_ = rowbufD[pj][1][pg*36 + pe0];
      const float d_ = rowbufD[pj][1][pg*36 + pe1];
      const float rdet = 1.0f / (a*d_ - b_*c_);
      const float i00 =  d_*rdet, i01 = -b_*rdet;
      const float i10 = -c_*rdet, i11 =  a*rdet;
      if (r == pc0 || r == pc1){
        // pivot rows: new row = (inv22 row) * raw panel; pivot cols get inv22 entries
        const float m0 = (r == pc0) ? i00 : i10;
        const float m1 = (r == pc0) ? i01 : i11;
        #pragma unroll
        for (int u = 0; u < 8; u++){
          float4 r0v = *(const float4*)&rowbufD[pj][0][g*36 + 4*u];
          float4 r1v = *(const float4*)&rowbufD[pj][1][g*36 + 4*u];
          #pragma unroll
          for (int e = 0; e < 4; e++){
            const int c = g*32 + 4*u + e;
            const float w0 = (e==0)?r0v.x:(e==1)?r0v.y:(e==2)?r0v.z:r0v.w;
            const float w1 = (e==0)?r1v.x:(e==1)?r1v.y:(e==2)?r1v.z:r1v.w;
            float nv = m0*w0 + m1*w1;
            if (c == pc0) nv = (r == pc0) ? i00 : i10;
            if (c == pc1) nv = (r == pc0) ? i01 : i11;
            reg[4*u+e] = nv;
          }
        }
      } else {
        const float w0 = colbufD[pj][0][r], w1 = colbufD[pj][1][r];
        const float f0 = w0*i00 + w1*i10;
        const float f1 = w0*i01 + w1*i11;
        #pragma unroll
        for (int u = 0; u < 8; u++){
          float4 r0v = *(const float4*)&rowbufD[pj][0][g*36 + 4*u];
          float4 r1v = *(const float4*)&rowbufD[pj][1][g*36 + 4*u];
          #pragma unroll
          for (int e = 0; e < 4; e++){
            const int c = g*32 + 4*u + e;
            const float q0 = (e==0)?r0v.x:(e==1)?r0v.y:(e==2)?r0v.z:r0v.w;
            const float q1 = (e==0)?r1v.x:(e==1)?r1v.y:(e==2)?r1v.z:r1v.w;
            float nv = fmaf(-f1, q1, fmaf(-f0, q0, reg[4*u+e]));
            if (c == pc0) nv = -f0;
            if (c == pc1) nv = -f1;
            reg[4*u+e] = nv;
          }
        }
      }
      // publish next epoch's raw rows/cols (post-update, parity pn)
      if (m + 1 < NB/2){
        const int pc0n = pc0 + 2, pc1n = pc1 + 2;
        if (g == (pc0n >> 5)){
          const int pe0n = pc0n & 31, pe1n = pc1n & 31;
          #pragma unroll
          for (int e2 = 0; e2 < 32; e2++){
            if (e2 == pe0n) colbufD[pn][0][r] = reg[e2];
            if (e2 == pe1n) colbufD[pn][1][r] = reg[e2];
          }
        }
        if (r == pc0n || r == pc1n){
          const int k = r & 1;
          #pragma unroll
          for (int u = 0; u < 8; u++)
            *(float4*)&rowbufD[pn][k][g*36 + 4*u] =
                make_float4(reg[4*u], reg[4*u+1], reg[4*u+2], reg[4*u+3]);
        }
      }
      __syncthreads();
    }
    // write P into Ps (and fp32 P for block 0) — vector stores, strip layout
    #pragma unroll
    for (int u = 0; u < 8; u++)
      *(float4*)&Ps[r*132 + g*32 + 4*u] =
          make_float4(reg[4*u], reg[4*u+1], reg[4*u+2], reg[4*u+3]);
    if (blockIdx.x == 0){
      #pragma unroll
      for (int u = 0; u < 8; u++)
        *(float4*)&P[r*NB + g*32 + 4*u] =
            make_float4(reg[4*u], reg[4*u+1], reg[4*u+2], reg[4*u+3]);
    }
  }
  __syncthreads();
  // ---- coalesced Ph/Pl writeout from Ps (block 0 only) ----
  if (blockIdx.x == 0){
    const int c = t >> 2, rbp = (t & 3) * 32;
    #pragma unroll
    for (int q4 = 0; q4 < 8; q4++){
      ushort h4[4], l4[4];
      #pragma unroll
      for (int e = 0; e < 4; e++){
        float v = Ps[(rbp + q4*4 + e)*132 + c];
        ushort h = f2bf(v);
        h4[e] = h; l4[e] = f2bf(v - bf2f(h));
      }
      *(ushort4*)(Ph + (size_t)c * NB + rbp + q4*4) = make_ushort4(h4[0], h4[1], h4[2], h4[3]);
      *(ushort4*)(Pl + (size_t)c * NB + rbp + q4*4) = make_ushort4(l4[0], l4[1], l4[2], l4[3]);
    }
  }
  // ---- panel GEMM: 2 j-tiles per block, one per 256-thread half ----
  const int half = t >> 8, tt = t & 255;
  const int j0 = blockIdx.x * 256 + half * 128;
  { // C split copy of M[:, kcol] panel (rows j0..j0+127) - pre-update values
    const int row = tt >> 1, hc = (tt & 1) * 64;
    const float* src = M + (size_t)(j0 + row) * NN + k0 + hc;
    ushort* dh = Ch + (size_t)(j0 + row) * NB + hc;
    ushort* dl = Cl + (size_t)(j0 + row) * NB + hc;
    #pragma unroll
    for (int u = 0; u < 16; u++){
      float4 v = ((const float4*)src)[u];
      ushort h0 = f2bf(v.x), h1 = f2bf(v.y), h2 = f2bf(v.z), h3 = f2bf(v.w);
      ((ushort4*)dh)[u] = make_ushort4(h0, h1, h2, h3);
      ((ushort4*)dl)[u] = make_ushort4(f2bf(v.x - bf2f(h0)), f2bf(v.y - bf2f(h1)),
                                       f2bf(v.z - bf2f(h2)), f2bf(v.w - bf2f(h3)));
    }
  }
  const int tx = tt & 15, ty = tt >> 4;
  float* myBs = Bs[half];
  float acc[8][8];
  #pragma unroll
  for (int u = 0; u < 8; u++)
    #pragma unroll
    for (int v = 0; v < 8; v++) acc[u][v] = 0.f;
  for (int ks = 0; ks < NB; ks += 16){
    {
      const int kkl = tt >> 4, c8 = (tt & 15) * 8;
      const float* pb = M + (size_t)(k0 + ks + kkl) * NN + j0 + c8;
      float4 b0 = ((const float4*)pb)[0];
      float4 b1 = ((const float4*)pb)[1];
      *(float4*)&myBs[kkl*132 + c8]     = b0;
      *(float4*)&myBs[kkl*132 + c8 + 4] = b1;
    }
    __syncthreads();
    #pragma unroll
    for (int kk = 0; kk < 16; kk++){
      float a[8], b[8];
      #pragma unroll
      for (int u = 0; u < 8; u++) a[u] = Ps[RMAP(ty,u)*132 + ks + kk];
      float4 b0 = *(const float4*)&myBs[kk*132 + tx*4];
      float4 b1 = *(const float4*)&myBs[kk*132 + tx*4 + 64];
      b[0]=b0.x; b[1]=b0.y; b[2]=b0.z; b[3]=b0.w;
      b[4]=b1.x; b[5]=b1.y; b[6]=b1.z; b[7]=b1.w;
      #pragma unroll
      for (int u = 0; u < 8; u++)
        #pragma unroll
        for (int v = 0; v < 8; v++) acc[u][v] += a[u] * b[v];
    }
    __syncthreads();
  }
  // write T fp32 (coalesced) + T transposed split
  #pragma unroll
  for (int u = 0; u < 8; u++){
    const int rr = RMAP(ty,u);
    float* pd = Tfm + (size_t)rr * NN + j0 + tx*4;
    *(float4*)pd        = make_float4(acc[u][0], acc[u][1], acc[u][2], acc[u][3]);
    *(float4*)(pd + 64) = make_float4(acc[u][4], acc[u][5], acc[u][6], acc[u][7]);
    #pragma unroll
    for (int v = 0; v < 8; v++){
      const int cc = j0 + CMAP(tx,v);
      float val = acc[u][v];
      ushort h = f2bf(val);
      Th[(size_t)cc * NB + rr] = h;
      Tl[(size_t)cc * NB + rr] = f2bf(val - bf2f(h));
    }
  }
}

// Trailing update (MFMA split-3) + chunked LDS-transpose epilogue (33.8 KB LDS -> 4 blk/CU)
__global__ __launch_bounds__(256) void k_gj_update(float* __restrict__ M0, float* __restrict__ M1,
    const float* __restrict__ Pbuf,
    const ushort* __restrict__ Pth, const ushort* __restrict__ Ptl,
    const float* __restrict__ Tf,
    const ushort* __restrict__ Tth, const ushort* __restrict__ Ttl,
    const ushort* __restrict__ Chh, const ushort* __restrict__ Chl, int kb){
  __shared__ __align__(16) float shchunk[64 * 132];   // 33.8 KB; staging aliased below (32 KB)
  ushort* tAh = (ushort*)shchunk;
  ushort* tAl = tAh + 4096;
  ushort* tBh = tAl + 4096;
  ushort* tBl = tBh + 4096;
  const int mat = blockIdx.z;
  float* M = mat ? M1 : M0;
  const float* P = Pbuf + (size_t)mat * NB * NB;
  const ushort* Ph = Pth + (size_t)mat * NB * NB;
  const ushort* Pl = Ptl + (size_t)mat * NB * NB;
  const float* Tfm = Tf + (size_t)mat * NB * NN;
  const ushort* Th = Tth + (size_t)mat * NN * NB;
  const ushort* Tl = Ttl + (size_t)mat * NN * NB;
  const ushort* Ch = Chh + (size_t)mat * NN * NB;
  const ushort* Cl = Chl + (size_t)mat * NN * NB;
  const int jb = blockIdx.x, ib = blockIdx.y;
  const int k0 = kb * NB, i0 = ib * NB, j0 = jb * NB;
  const int t = threadIdx.x;
  if (ib == kb){
    const int row = t >> 1, half = (t & 1) * 64;
    float* dst = M + (size_t)(k0 + row) * NN + j0 + half;
    if (jb == kb){
      const float* src = P + (size_t)row * NB + half;
      #pragma unroll
      for (int u = 0; u < 16; u++) ((float4*)dst)[u] = ((const float4*)src)[u];
    } else {
      const float* src = Tfm + (size_t)row * NN + j0 + half;
      #pragma unroll
      for (int u = 0; u < 16; u++) ((float4*)dst)[u] = ((const float4*)src)[u];
    }
    return;
  }
  const int L = t & 63, w = t >> 6;
  const int wr = w >> 1, wc = w & 1;
  const int lm = L & 15, quad = L >> 4;
  const int sch = (t & 3) * 8;
  const ushort* Bh = (jb == kb) ? Ph : (Th + (size_t)j0 * NB);
  const ushort* Bl = (jb == kb) ? Pl : (Tl + (size_t)j0 * NB);
  const ushort* Ahp = Ch + (size_t)i0 * NB;
  const ushort* Alp = Cl + (size_t)i0 * NB;
  f32x4 acc[4][4];
  #pragma unroll
  for (int i = 0; i < 4; i++)
    #pragma unroll
    for (int j = 0; j < 4; j++) acc[i][j] = (f32x4){0.f, 0.f, 0.f, 0.f};
  for (int ks = 0; ks < NB; ks += 32){
    #pragma unroll
    for (int p = 0; p < 2; p++){
      const int row = p*64 + (t >> 2);
      const size_t ga = (size_t)row * NB + ks + sch;
      const int lo = row*32 + sch;
      stage16(Ahp + ga, tAh + lo);
      stage16(Alp + ga, tAl + lo);
      stage16(Bh + ga, tBh + lo);
      stage16(Bl + ga, tBl + lo);
    }
    __syncthreads();
    bf16x8 ah[4], al[4], bh[4], bl[4];
    #pragma unroll
    for (int i = 0; i < 4; i++){
      const int ao = (wr*64 + i*16 + lm)*32 + quad*8;
      const int bo = (wc*64 + i*16 + lm)*32 + quad*8;
      ah[i] = *(const bf16x8*)&tAh[ao];
      al[i] = *(const bf16x8*)&tAl[ao];
      bh[i] = *(const bf16x8*)&tBh[bo];
      bl[i] = *(const bf16x8*)&tBl[bo];
    }
    #pragma unroll
    for (int i = 0; i < 4; i++)
      #pragma unroll
      for (int j = 0; j < 4; j++){
        acc[i][j] = __builtin_amdgcn_mfma_f32_16x16x32_bf16(ah[i], bh[j], acc[i][j], 0, 0, 0);
        acc[i][j] = __builtin_amdgcn_mfma_f32_16x16x32_bf16(ah[i], bl[j], acc[i][j], 0, 0, 0);
        acc[i][j] = __builtin_amdgcn_mfma_f32_16x16x32_bf16(al[i], bh[j], acc[i][j], 0, 0, 0);
      }
    __syncthreads();
  }
  // chunked transpose: 2 passes of 64 rows through 33.8 KB LDS, coalesced float4 RMW
  const int rloc = t >> 2, cg = (t & 3) * 4;
  const int jc0 = (jb == kb) ? k0 : j0;
  #pragma unroll 1
  for (int hp = 0; hp < 2; hp++){
    if (wr == hp){
      #pragma unroll
      for (int i = 0; i < 4; i++)
        #pragma unroll
        for (int j = 0; j < 4; j++)
          #pragma unroll
          for (int rg = 0; rg < 4; rg++){
            const int row = i*16 + quad*4 + rg;       // local 0..63
            const int col = wc*64 + j*16 + lm;
            shchunk[row*132 + col] = acc[i][j][rg];
          }
    }
    __syncthreads();
    float* pm = M + (size_t)(i0 + hp*64 + rloc) * NN + jc0;
    if (jb == kb){
      #pragma unroll
      for (int c = 0; c < 8; c++){
        const int col = cg + 16*c;
        float4 v = *(float4*)&shchunk[rloc*132 + col];
        *(float4*)(pm + col) = make_float4(-v.x, -v.y, -v.z, -v.w);
      }
    } else {
      #pragma unroll
      for (int c = 0; c < 8; c++){
        const int col = cg + 16*c;
        float4 v = *(float4*)&shchunk[rloc*132 + col];
        float4 m = *(float4*)(pm + col);
        m.x -= v.x; m.y -= v.y; m.z -= v.z; m.w -= v.w;
        *(float4*)(pm + col) = m;
      }
    }
    __syncthreads();
  }
}

// ---------------- final combine ----------------
__global__ void k_combine(const float* __restrict__ slots, float* __restrict__ out){
  if (threadIdx.x == 0 && blockIdx.x == 0){
    const double invN2 = 1.0 / ((double)NN * (double)NN);
    double term1 = ((double)slots[0] + (double)slots[1] - 2.0 * (double)slots[2]) * invN2;
    double pairs = 0.0;
    for (int p = 0; p < 3; p++){
      const float* s = slots + 4 + 5 * p;
      pairs += ((double)s[0] - 0.2 * (double)s[1] + (double)s[2] - 0.2 * (double)s[3] - 2.0 * (double)s[4]);
    }
    out[0] = (float)(1.0 * term1 + 500.0 * pairs * invN2);
    out[1] = (float)((double)slots[3] / (2.0 * (double)NN));
  }
}

// ---------------- host ----------------
extern "C" void kernel_launch(void* const* d_in, const int* in_sizes, int n_in,
                              void* d_out, int out_size, void* d_ws, size_t ws_size,
                              hipStream_t stream){
  const float* x    = (const float*)d_in[0];
  const float* z    = (const float*)d_in[1];
  const float* zz   = (const float*)d_in[2];
  const float* xx   = (const float*)d_in[3];
  const float* stdn = (const float*)d_in[4];
  float* out = (float*)d_out;
  float* ws  = (float*)d_ws;

  const size_t NN2 = (size_t)NN * NN;
  float* R0 = ws;
  float* R1 = R0 + NN2;
  float* R2 = R1 + NN2;
  float* PanelF = R2 + NN2;
  ushort* Tth = (ushort*)PanelF;                       // 2 MB
  ushort* Ttl = Tth + 2 * (size_t)NB * NN;
  ushort* Chh = Ttl + 2 * (size_t)NB * NN;
  ushort* Chl = Chh + 2 * (size_t)NB * NN;             // panels total 8 MB
  float* Tf   = (float*)(Chl + 2 * (size_t)NB * NN);   // 4 MB fp32 T (2 mats)
  float* Pb   = Tf + 2 * (size_t)NB * NN;              // fp32 P (2 mats)
  ushort* Pth = (ushort*)(Pb + 2 * (size_t)NB * NB);
  ushort* Ptl = Pth + 2 * (size_t)NB * NB;
  float* slots= (float*)(Ptl + 2 * (size_t)NB * NB);
  float* stdsq= slots + 32;
  float* zrs  = stdsq + NN;
  float* nzz  = zrs + (size_t)NN * NV;
  float* nz8  = nzz + (size_t)NV * NN;
  float* nrmz = nz8 + (size_t)NV * NN;

  ushort* R0h = (ushort*)R0;   // B hi (bf16)
  ushort* R2h = (ushort*)R2;   // A hi (bf16)
  ushort* Vh  = (ushort*)R1;   // V hi (bf16, lower half of R1)
  ushort* QPh = Vh + NN2;      // Kqp bf16 (upper half of R1)

  dim3 g32(NBLK, NBLK);

  k_zero<<<1, 64, 0, stream>>>(slots, 32);
  k_norms<<<(NN * NV) / 256, 256, 0, stream>>>(z, zz, stdn, stdsq, zrs, nzz, nz8);
  k_rownorm<<<NN / 256, 256, 0, stream>>>(nz8, nrmz);
  k_nll<<<1024, 256, 0, stream>>>(x, xx, slots);
  k_sqq<<<NTRI, 256, 0, stream>>>(z, nrmz, slots);
  k_spp_sqp<<<g32, 256, 0, stream>>>(stdn, stdsq, zrs, nrmz, slots);

  const float* zz0 = zz;            const float* z0 = z;
  const float* zz1 = zz + VD;       const float* z1 = z + VD;
  const float* nzz0 = nzz;          const float* nz0 = nz8;
  const float* nzz1 = nzz + NN;     const float* nz1 = nz8 + NN;

  for (int b = 1; b <= 2; b++){
    const float* zzb = zz + b*VD;  const float* nzzb = nzz + (size_t)b*NN;
    const float* zb  = z + b*VD;   const float* nzb  = nz8 + (size_t)b*NN;
    k_rbf<<<g32, 256, 0, stream>>>(zzb, zzb, nzzb, nzzb, 0.2f, R0);
    k_rbf<<<g32, 256, 0, stream>>>(zb,  zb,  nzb,  nzb,  0.2f, R1);
    for (int kb = 0; kb < NBLK; kb++){
      k_gj_diagpanel<<<dim3(16, 2), 512, 0, stream>>>(R0, R1, Pb, Pth, Ptl,
                                                      Tf, Tth, Ttl, Chh, Chl, kb);
      k_gj_update<<<dim3(NBLK, NBLK, 2), 256, 0, stream>>>(R0, R1, Pb, Pth, Ptl,
                                                           Tf, Tth, Ttl, Chh, Chl, kb);
    }
    // bf16 casts: A -> R2h, B -> R0h (B fp32 in R1 dead after)
    k_split<<<16384, 256, 0, stream>>>(R0, R2h);
    k_split<<<16384, 256, 0, stream>>>(R1, R0h);
    // Kqp bf16 precompute: QP[n][l] = k(zz_n, z_l), into upper half of R1
    k_rbf16<<<g32, 256, 0, stream>>>(zzb, zb, nzzb, nzb, QPh);
    // V = B * QP^T (plain bf16 GEMM); dest Vh (lower half of R1)
    k_mfma_gemm<<<g32, 256, 0, stream>>>(R0h, QPh, Vh);
    // trace GEMMs (pure bf16) with fused tr(L*A) reduction
    if (b == 1){
      k_mfma_tr<<<NTRI, 256, 0, stream>>>(R2h, R2h, 1, 1, 1,
                                          zz0, zz0, nzz0, nzz0, 5, 4,
                                          nullptr, nullptr, nullptr, nullptr, 0, 0, slots);
      k_mfma_tr<<<NTRI, 256, 0, stream>>>(R0h, R0h, 1, 1, 1,
                                          z0, z0, nz0, nz0, 7, 6,
                                          nullptr, nullptr, nullptr, nullptr, 0, 0, slots);
      k_mfma_tr<<<g32, 256, 0, stream>>>(R2h, Vh, 0, 0, 1,
                                         zz0, z0, nzz0, nz0, 8, 0,
                                         nullptr, nullptr, nullptr, nullptr, 0, 0, slots);
    } else {
      k_mfma_tr<<<NTRI, 256, 0, stream>>>(R2h, R2h, 1, 1, 2,
                                          zz1, zz1, nzz1, nzz1, 10, 9,
                                          zz0, zz0, nzz0, nzz0, 15, 14, slots);
      k_mfma_tr<<<NTRI, 256, 0, stream>>>(R0h, R0h, 1, 1, 2,
                                          z1, z1, nz1, nz1, 12, 11,
                                          z0, z0, nz0, nz0, 17, 16, slots);
      k_mfma_tr<<<g32, 256, 0, stream>>>(R2h, Vh, 0, 0, 2,
                                         zz1, z1, nzz1, nz1, 13, 0,
                                         zz0, z0, nzz0, nz0, 18, 0, slots);
    }
  }
  k_combine<<<1, 1, 0, stream>>>(slots, out);
}

// Round 10
// 12708.392 us; speedup vs baseline: 3.7844x; 1.1873x over previous
//
#include <hip/hip_runtime.h>
#include <math.h>

// Problem constants (fixed by setup_inputs)
#define NN 4096      // N samples
#define DD 256       // flat endo dim (8 vars * 32)
#define NV 8         // vars
#define VD 32        // per-var dim
#define NB 128       // GJ block size
#define NBLK (NN/NB) // 32
#define NTRI (NBLK*(NBLK+1)/2)  // 528

// fp32-GEMM output ownership mapping (bank-conflict-free)
#define RMAP(ty,u) ((ty)*4 + (((u)>>2)<<6) + ((u)&3))
#define CMAP(tx,v) ((tx)*4 + (((v)>>2)<<6) + ((v)&3))

typedef __attribute__((ext_vector_type(8))) short bf16x8;
typedef __attribute__((ext_vector_type(4))) float f32x4;

#define AS1(p) ((const __attribute__((address_space(1))) void*)(p))
#define AS3(p) ((__attribute__((address_space(3))) void*)(p))

__device__ __forceinline__ void stage16(const ushort* g, ushort* l){
  __builtin_amdgcn_global_load_lds(AS1(g), AS3(l), 16, 0, 0);
}

__device__ __forceinline__ ushort f2bf(float x){
  uint u = __float_as_uint(x);
  u += 0x7FFFu + ((u >> 16) & 1u);
  return (ushort)(u >> 16);
}
__device__ __forceinline__ float bf2f(ushort h){ return __uint_as_float(((uint)h) << 16); }

// triangular block map: p -> (bi >= bj)
__device__ __forceinline__ void tri_map(int p, int& bi, int& bj){
  int b = (int)((sqrtf(8.0f * (float)p + 1.0f) - 1.0f) * 0.5f);
  while ((b + 1) * (b + 2) / 2 <= p) b++;
  while (b * (b + 1) / 2 > p) b--;
  bi = b; bj = p - b * (b + 1) / 2;
}

// ---------------- helpers ----------------
__device__ __forceinline__ void block_atomic_add(float v, float* red, float* dst){
  #pragma unroll
  for (int off = 32; off > 0; off >>= 1) v += __shfl_down(v, off, 64);
  const int lane = threadIdx.x & 63;
  const int w = threadIdx.x >> 6;
  if (lane == 0) red[w] = v;
  __syncthreads();
  if (threadIdx.x == 0) atomicAdd(dst, red[0] + red[1] + red[2] + red[3]);
  __syncthreads();
}

// shared staging macros for the bf16 MFMA GEMM main loops
#define STAGE_AB(tAp, tBp, kk) do { \
  _Pragma("unroll") \
  for (int p_ = 0; p_ < 2; p_++){ \
    const int row_ = p_*64 + (t >> 2); \
    const int lo_ = row_*32 + sch; \
    stage16(Ah + (size_t)(r0 + row_) * NN + (kk) + sch, (tAp) + lo_); \
    stage16(Bh + (size_t)(c0 + row_) * NN + (kk) + sch, (tBp) + lo_); \
  } } while(0)

#define MFMA_STEP(tAp, tBp) do { \
  bf16x8 ah_[4], bh_[4]; \
  _Pragma("unroll") \
  for (int i_ = 0; i_ < 4; i_++){ \
    ah_[i_] = *(const bf16x8*)&(tAp)[(wr*64 + i_*16 + lm)*32 + quad*8]; \
    bh_[i_] = *(const bf16x8*)&(tBp)[(wc*64 + i_*16 + lm)*32 + quad*8]; \
  } \
  _Pragma("unroll") \
  for (int i_ = 0; i_ < 4; i_++) \
    _Pragma("unroll") \
    for (int j_ = 0; j_ < 4; j_++) \
      acc[i_][j_] = __builtin_amdgcn_mfma_f32_16x16x32_bf16(ah_[i_], bh_[j_], acc[i_][j_], 0, 0, 0); \
  } while(0)

// counted-vmcnt pipelined step (T3+T4): raw barrier, NO vmcnt(0) drain in main loop.
#define PIPE_WAIT_BAR(N) do { \
  asm volatile("s_waitcnt vmcnt(" #N ")" ::: "memory"); \
  __builtin_amdgcn_s_barrier(); \
  } while(0)
#define PIPE_BAR() do { \
  asm volatile("" ::: "memory"); \
  __builtin_amdgcn_s_barrier(); \
  asm volatile("" ::: "memory"); \
  } while(0)

// Depth-3 ring main loop over NN/32 = 128 K-steps.
#define PIPE_MAIN_LOOP() do { \
  STAGE_AB(shb + 0*8192, shb + 0*8192 + 4096, 0); \
  STAGE_AB(shb + 1*8192, shb + 1*8192 + 4096, 32); \
  STAGE_AB(shb + 2*8192, shb + 2*8192 + 4096, 64); \
  int cur = 0; \
  _Pragma("unroll 1") \
  for (int step = 0; step < 125; step++){ \
    ushort* tA = shb + cur*8192; ushort* tB = tA + 4096; \
    PIPE_WAIT_BAR(8); \
    MFMA_STEP(tA, tB); \
    PIPE_BAR(); \
    STAGE_AB(tA, tB, (step+3)*32); \
    cur++; if (cur == 3) cur = 0; \
  } \
  { ushort* tA = shb + cur*8192; ushort* tB = tA + 4096; \
    PIPE_WAIT_BAR(8); MFMA_STEP(tA, tB); cur++; if (cur == 3) cur = 0; } \
  { ushort* tA = shb + cur*8192; ushort* tB = tA + 4096; \
    PIPE_WAIT_BAR(4); MFMA_STEP(tA, tB); cur++; if (cur == 3) cur = 0; } \
  { ushort* tA = shb + cur*8192; ushort* tB = tA + 4096; \
    PIPE_WAIT_BAR(0); MFMA_STEP(tA, tB); } \
  } while(0)

// ---------------- small utility kernels ----------------
__global__ void k_zero(float* p, int n){
  int i = blockIdx.x * blockDim.x + threadIdx.x;
  if (i < n) p[i] = 0.f;
}

__global__ void k_norms(const float* __restrict__ z, const float* __restrict__ zz,
                        const float* __restrict__ stdn,
                        float* __restrict__ stdsq, float* __restrict__ zrs,
                        float* __restrict__ nzz, float* __restrict__ nz8){
  int t = blockIdx.x * blockDim.x + threadIdx.x;
  if (t >= NN * NV) return;
  int i = t / NV, v = t % NV;
  const float* zp  = z  + (size_t)i * DD + v * VD;
  const float* zzp = zz + (size_t)i * DD + v * VD;
  float s1 = 0.f, s2 = 0.f, s2z = 0.f;
  #pragma unroll
  for (int k = 0; k < VD; k++){
    float a = zp[k];  s1 += a; s2 += a * a;
    float b = zzp[k]; s2z += b * b;
  }
  zrs[(size_t)i * NV + v] = s1;
  nz8[(size_t)v * NN + i] = s2;
  nzz[(size_t)v * NN + i] = s2z;
  if (v == 0){
    float s = 0.f;
    #pragma unroll
    for (int u = 0; u < NV; u++){ float a = stdn[(size_t)i * NV + u]; s += a * a; }
    stdsq[i] = s;
  }
}

__global__ void k_rownorm(const float* __restrict__ nz8, float* __restrict__ nrmz){
  int i = blockIdx.x * blockDim.x + threadIdx.x;
  if (i < NN){
    float s = 0.f;
    #pragma unroll
    for (int v = 0; v < NV; v++) s += nz8[(size_t)v * NN + i];
    nrmz[i] = s;
  }
}

__global__ __launch_bounds__(256) void k_nll(const float* __restrict__ x,
                                             const float* __restrict__ xx,
                                             float* __restrict__ slots){
  __shared__ float red[4];
  float s = 0.f;
  const int total = NN * DD;
  for (int i = (blockIdx.x * 256 + threadIdx.x) * 4; i < total; i += gridDim.x * 256 * 4){
    float4 a = *(const float4*)(x + i);
    float4 b = *(const float4*)(xx + i);
    float d0 = b.x - a.x, d1 = b.y - a.y, d2 = b.z - a.z, d3 = b.w - a.w;
    s += d0*d0 + d1*d1 + d2*d2 + d3*d3;
  }
  block_atomic_add(s, red, slots + 3);
}

// ---------------- first (exo-free) MMD term ----------------
__global__ __launch_bounds__(256) void k_sqq(const float* __restrict__ z,
                                             const float* __restrict__ nrm,
                                             float* __restrict__ slots){
  __shared__ float Xr[128 * 33];
  __shared__ float Xc[128 * 33];
  __shared__ float red[4];
  int bi, bj; tri_map(blockIdx.x, bi, bj);
  const int r0 = bi * 128, c0 = bj * 128;
  const float wgt = (bi != bj) ? 2.f : 1.f;
  const int t = threadIdx.x;
  const int tx = t & 15, ty = t >> 4;
  const int lrow = t >> 1, lh = t & 1;
  float acc[8][8];
  #pragma unroll
  for (int u = 0; u < 8; u++)
    #pragma unroll
    for (int v = 0; v < 8; v++) acc[u][v] = 0.f;
  for (int ks = 0; ks < DD; ks += 32){
    const float* pr = z + (size_t)(r0 + lrow) * DD + ks + lh * 16;
    const float* pc = z + (size_t)(c0 + lrow) * DD + ks + lh * 16;
    float* dr = &Xr[lrow * 33 + lh * 16];
    float* dc = &Xc[lrow * 33 + lh * 16];
    #pragma unroll
    for (int u = 0; u < 4; u++){
      float4 a = ((const float4*)pr)[u];
      dr[4*u+0] = a.x; dr[4*u+1] = a.y; dr[4*u+2] = a.z; dr[4*u+3] = a.w;
      float4 b = ((const float4*)pc)[u];
      dc[4*u+0] = b.x; dc[4*u+1] = b.y; dc[4*u+2] = b.z; dc[4*u+3] = b.w;
    }
    __syncthreads();
    #pragma unroll
    for (int kk = 0; kk < 32; kk++){
      float a[8], b[8];
      #pragma unroll
      for (int u = 0; u < 8; u++) a[u] = Xr[RMAP(ty,u)*33 + kk];
      #pragma unroll
      for (int v = 0; v < 8; v++) b[v] = Xc[CMAP(tx,v)*33 + kk];
      #pragma unroll
      for (int u = 0; u < 8; u++)
        #pragma unroll
        for (int v = 0; v < 8; v++) acc[u][v] += a[u] * b[v];
    }
    __syncthreads();
  }
  float s = 0.f;
  #pragma unroll 1
  for (int u = 0; u < 8; u++){
    const float ni = nrm[r0 + RMAP(ty,u)];
    #pragma unroll 1
    for (int v = 0; v < 8; v++)
      s += __expf(-(ni + nrm[c0 + CMAP(tx,v)] - 2.f * acc[u][v]) * (1.f/2048.f));
  }
  block_atomic_add(s * wgt, red, slots + 0);
}

__global__ __launch_bounds__(256) void k_spp_sqp(const float* __restrict__ stdn,
                                                 const float* __restrict__ stdsq,
                                                 const float* __restrict__ zrs,
                                                 const float* __restrict__ nrmz,
                                                 float* __restrict__ slots){
  __shared__ float sI[128*9], sJ[128*9], zI[128*9];
  __shared__ float qI[128], qJ[128], nI[128];
  __shared__ float red[4];
  const int r0 = blockIdx.y * 128, c0 = blockIdx.x * 128;
  const int t = threadIdx.x;
  if (t < 128){
    #pragma unroll
    for (int v = 0; v < 8; v++){
      sI[t*9+v] = stdn[(size_t)(r0+t)*NV + v];
      sJ[t*9+v] = stdn[(size_t)(c0+t)*NV + v];
      zI[t*9+v] = zrs[(size_t)(r0+t)*NV + v];
    }
    qI[t] = stdsq[r0+t]; qJ[t] = stdsq[c0+t]; nI[t] = nrmz[r0+t];
  }
  __syncthreads();
  const int tx = t & 15, ty = t >> 4;
  float spp = 0.f, sqp = 0.f;
  #pragma unroll 1
  for (int u = 0; u < 8; u++){
    int i = ty + 16*u;
    #pragma unroll 1
    for (int v = 0; v < 8; v++){
      int j = tx + 16*v;
      float dpp = 0.f, dqp = 0.f;
      #pragma unroll
      for (int k = 0; k < 8; k++){
        float sj = sJ[j*9+k];
        dpp += sI[i*9+k] * sj;
        dqp += zI[i*9+k] * sj;
      }
      spp += __expf(-(qI[i] + qJ[j] - 2.f*dpp) * (1.f/64.f));
      sqp += __expf(-(nI[i] + 32.f*qJ[j] - 2.f*dqp) * (1.f/2048.f));
    }
  }
  block_atomic_add(spp, red, slots + 1);
  block_atomic_add(sqp, red, slots + 2);
}

// ---------------- RBF Gram matrix build (K=32, fp32 out) ----------------
__global__ __launch_bounds__(256) void k_rbf(const float* __restrict__ Xr_,
                                             const float* __restrict__ Xc_,
                                             const float* __restrict__ nr,
                                             const float* __restrict__ nc,
                                             float lam, float* __restrict__ M){
  __shared__ float Xr[128 * 33];
  __shared__ float Xc[128 * 33];
  const int r0 = blockIdx.y * 128, c0 = blockIdx.x * 128;
  const int t = threadIdx.x;
  const int tx = t & 15, ty = t >> 4;
  const int lrow = t >> 1, lh = t & 1;
  {
    const float* pr = Xr_ + (size_t)(r0 + lrow) * DD + lh * 16;
    const float* pc = Xc_ + (size_t)(c0 + lrow) * DD + lh * 16;
    float* dr = &Xr[lrow * 33 + lh * 16];
    float* dc = &Xc[lrow * 33 + lh * 16];
    #pragma unroll
    for (int u = 0; u < 4; u++){
      float4 a = ((const float4*)pr)[u];
      dr[4*u+0]=a.x; dr[4*u+1]=a.y; dr[4*u+2]=a.z; dr[4*u+3]=a.w;
      float4 b = ((const float4*)pc)[u];
      dc[4*u+0]=b.x; dc[4*u+1]=b.y; dc[4*u+2]=b.z; dc[4*u+3]=b.w;
    }
  }
  __syncthreads();
  #pragma unroll 1
  for (int u = 0; u < 8; u++){
    const int gi = r0 + RMAP(ty,u);
    const float* xi = &Xr[RMAP(ty,u)*33];
    const float ni = nr[gi];
    float vals[8];
    #pragma unroll 1
    for (int v = 0; v < 8; v++){
      const int gj = c0 + CMAP(tx,v);
      const float* xj = &Xc[CMAP(tx,v)*33];
      float d = 0.f;
      #pragma unroll
      for (int k = 0; k < 32; k++) d += xi[k] * xj[k];
      float e = __expf(-(ni + nc[gj] - 2.f*d) * (1.f/32.f));
      if (gi == gj) e += lam;
      vals[v] = e;
    }
    float* pd = M + (size_t)gi * NN + c0 + tx*4;
    *(float4*)pd        = make_float4(vals[0], vals[1], vals[2], vals[3]);
    *(float4*)(pd + 64) = make_float4(vals[4], vals[5], vals[6], vals[7]);
  }
}

// ---------------- RBF Gram matrix build (K=32, bf16 out, no diag reg) ----------------
__global__ __launch_bounds__(256) void k_rbf16(const float* __restrict__ Xr_,
                                               const float* __restrict__ Xc_,
                                               const float* __restrict__ nr,
                                               const float* __restrict__ nc,
                                               ushort* __restrict__ Mh){
  __shared__ float Xr[128 * 33];
  __shared__ float Xc[128 * 33];
  const int r0 = blockIdx.y * 128, c0 = blockIdx.x * 128;
  const int t = threadIdx.x;
  const int tx = t & 15, ty = t >> 4;
  const int lrow = t >> 1, lh = t & 1;
  {
    const float* pr = Xr_ + (size_t)(r0 + lrow) * DD + lh * 16;
    const float* pc = Xc_ + (size_t)(c0 + lrow) * DD + lh * 16;
    float* dr = &Xr[lrow * 33 + lh * 16];
    float* dc = &Xc[lrow * 33 + lh * 16];
    #pragma unroll
    for (int u = 0; u < 4; u++){
      float4 a = ((const float4*)pr)[u];
      dr[4*u+0]=a.x; dr[4*u+1]=a.y; dr[4*u+2]=a.z; dr[4*u+3]=a.w;
      float4 b = ((const float4*)pc)[u];
      dc[4*u+0]=b.x; dc[4*u+1]=b.y; dc[4*u+2]=b.z; dc[4*u+3]=b.w;
    }
  }
  __syncthreads();
  #pragma unroll 1
  for (int u = 0; u < 8; u++){
    const int gi = r0 + RMAP(ty,u);
    const float* xi = &Xr[RMAP(ty,u)*33];
    const float ni = nr[gi];
    ushort vals[8];
    #pragma unroll 1
    for (int v = 0; v < 8; v++){
      const int gj = c0 + CMAP(tx,v);
      const float* xj = &Xc[CMAP(tx,v)*33];
      float d = 0.f;
      #pragma unroll
      for (int k = 0; k < 32; k++) d += xi[k] * xj[k];
      vals[v] = f2bf(__expf(-(ni + nc[gj] - 2.f*d) * (1.f/32.f)));
    }
    ushort* pd = Mh + (size_t)gi * NN + c0 + tx*4;
    *(ushort4*)pd        = make_ushort4(vals[0], vals[1], vals[2], vals[3]);
    *(ushort4*)(pd + 64) = make_ushort4(vals[4], vals[5], vals[6], vals[7]);
  }
}

// ---------------- fp32 -> bf16 (hi only; trace GEMMs run pure bf16) ----------------
__global__ __launch_bounds__(256) void k_split(const float* __restrict__ S,
                                               ushort* __restrict__ H){
  size_t i = ((size_t)blockIdx.x * 256 + threadIdx.x) * 4;
  float4 x = *(const float4*)(S + i);
  *(ushort4*)(H + i) = make_ushort4(f2bf(x.x), f2bf(x.y), f2bf(x.z), f2bf(x.w));
}

// ---------------- MFMA bf16 GEMM + fused RBF-trace epilogue(s) + fused tr(L*A) ----
__global__ __launch_bounds__(256) void k_mfma_tr(
    const ushort* __restrict__ Ah, const ushort* __restrict__ Bh,
    int sym, int doRed, int nepi,
    const float* e0xr, const float* e0xc, const float* e0nr, const float* e0nc, int s0, int rs0,
    const float* e1xr, const float* e1xc, const float* e1nr, const float* e1nc, int s1, int rs1,
    float* __restrict__ slots){
  __shared__ __align__(16) ushort shb[24576];   // 48 KB: 3-deep staging ring / epilogue X tiles
  __shared__ float red[4];
  int bi, bj;
  if (sym){
    int p = blockIdx.x;
    p = (p & 7) * (NTRI/8) + (p >> 3);
    tri_map(p, bi, bj);
  } else {
    int id = blockIdx.y * NBLK + blockIdx.x;
    id = (id & 7) * ((NBLK*NBLK)/8) + (id >> 3);
    bi = id / NBLK; bj = id % NBLK;
  }
  const int r0 = bi * 128, c0 = bj * 128;
  const float wgt = (sym && bi != bj) ? 2.f : 1.f;
  const int t = threadIdx.x;
  const int L = t & 63, w = t >> 6;
  const int wr = w >> 1, wc = w & 1;
  const int lm = L & 15, quad = L >> 4;
  const int sch = (t & 3) * 8;

  f32x4 acc[4][4];
  #pragma unroll
  for (int i = 0; i < 4; i++)
    #pragma unroll
    for (int j = 0; j < 4; j++) acc[i][j] = (f32x4){0.f, 0.f, 0.f, 0.f};

  PIPE_MAIN_LOOP();
  __syncthreads();   // full drain; staging ring now dead -> reuse for epilogue X tiles

  // -------- fused RBF-trace epilogue(s) --------
  #pragma unroll 1
  for (int e = 0; e < nepi; e++){
    const float* xr = e ? e1xr : e0xr;
    const float* xc = e ? e1xc : e0xc;
    const float* nr = e ? e1nr : e0nr;
    const float* nc = e ? e1nc : e0nc;
    const int slot = e ? s1 : s0;
    const int rslot = e ? rs1 : rs0;
    ushort* Xrh = shb;          // [128][32] bf16 hi
    ushort* Xrl = shb + 4096;   // lo
    ushort* Xch = shb + 8192;
    ushort* Xcl = shb + 12288;
    {
      const int lr = t >> 1, lh = (t & 1) * 16;
      const float* pr = xr + (size_t)(r0 + lr) * DD + lh;
      const float* pc = xc + (size_t)(c0 + lr) * DD + lh;
      ushort* drh = Xrh + lr*32 + lh;  ushort* drl = Xrl + lr*32 + lh;
      ushort* dch = Xch + lr*32 + lh;  ushort* dcl = Xcl + lr*32 + lh;
      #pragma unroll
      for (int u = 0; u < 4; u++){
        float4 a = ((const float4*)pr)[u];
        ushort h0 = f2bf(a.x), h1 = f2bf(a.y), h2 = f2bf(a.z), h3 = f2bf(a.w);
        ((ushort4*)drh)[u] = make_ushort4(h0, h1, h2, h3);
        ((ushort4*)drl)[u] = make_ushort4(f2bf(a.x - bf2f(h0)), f2bf(a.y - bf2f(h1)),
                                          f2bf(a.z - bf2f(h2)), f2bf(a.w - bf2f(h3)));
        float4 b = ((const float4*)pc)[u];
        ushort g0 = f2bf(b.x), g1 = f2bf(b.y), g2 = f2bf(b.z), g3 = f2bf(b.w);
        ((ushort4*)dch)[u] = make_ushort4(g0, g1, g2, g3);
        ((ushort4*)dcl)[u] = make_ushort4(f2bf(b.x - bf2f(g0)), f2bf(b.y - bf2f(g1)),
                                          f2bf(b.z - bf2f(g2)), f2bf(b.w - bf2f(g3)));
      }
    }
    __syncthreads();
    float s = 0.f, s2 = 0.f;
    #pragma unroll 1
    for (int i = 0; i < 4; i++){
      const int ao = (wr*64 + i*16 + lm)*32 + quad*8;
      const bf16x8 ahh = *(const bf16x8*)&Xrh[ao];
      const bf16x8 ahl = *(const bf16x8*)&Xrl[ao];
      f32x4 dj[4];
      #pragma unroll
      for (int j = 0; j < 4; j++){
        const int bo = (wc*64 + j*16 + lm)*32 + quad*8;
        bf16x8 bhh = *(const bf16x8*)&Xch[bo];
        bf16x8 bhl = *(const bf16x8*)&Xcl[bo];
        f32x4 dd = (f32x4){0.f, 0.f, 0.f, 0.f};
        dd = __builtin_amdgcn_mfma_f32_16x16x32_bf16(ahh, bhh, dd, 0, 0, 0);
        dd = __builtin_amdgcn_mfma_f32_16x16x32_bf16(ahl, bhh, dd, 0, 0, 0);
        dd = __builtin_amdgcn_mfma_f32_16x16x32_bf16(ahh, bhl, dd, 0, 0, 0);
        dj[j] = dd;
      }
      #pragma unroll
      for (int rg = 0; rg < 4; rg++){
        const int rl = wr*64 + i*16 + quad*4 + rg;
        const float ni = nr[r0 + rl];
        #pragma unroll
        for (int j = 0; j < 4; j++){
          const int cl = wc*64 + j*16 + lm;
          const float Lval = __expf(-(ni + nc[c0 + cl] - 2.f*dj[j][rg]) * (1.f/32.f));
          s += acc[i][j][rg] * Lval;
          if (doRed) s2 += bf2f(Ah[(size_t)(r0 + rl) * NN + c0 + cl]) * Lval;
        }
      }
    }
    block_atomic_add(s * wgt, red, slots + slot);
    if (doRed) block_atomic_add(s2 * wgt, red, slots + rslot);
    __syncthreads();
  }
}

// ---------------- plain MFMA bf16 GEMM, bf16 store (V = B * QP^T-row layout) ----------
__global__ __launch_bounds__(256) void k_mfma_gemm(
    const ushort* __restrict__ Ah, const ushort* __restrict__ Bh,
    ushort* __restrict__ Dh){
  __shared__ __align__(16) ushort shb[24576];   // 48 KB 3-deep staging ring
  int id = blockIdx.y * NBLK + blockIdx.x;
  id = (id & 7) * ((NBLK*NBLK)/8) + (id >> 3);
  const int r0 = (id / NBLK) * 128, c0 = (id % NBLK) * 128;
  const int t = threadIdx.x;
  const int L = t & 63, w = t >> 6;
  const int wr = w >> 1, wc = w & 1;
  const int lm = L & 15, quad = L >> 4;
  const int sch = (t & 3) * 8;
  f32x4 acc[4][4];
  #pragma unroll
  for (int i = 0; i < 4; i++)
    #pragma unroll
    for (int j = 0; j < 4; j++) acc[i][j] = (f32x4){0.f, 0.f, 0.f, 0.f};
  PIPE_MAIN_LOOP();
  #pragma unroll
  for (int i = 0; i < 4; i++)
    #pragma unroll
    for (int j = 0; j < 4; j++)
      #pragma unroll
      for (int rg = 0; rg < 4; rg++){
        const int row = wr*64 + i*16 + quad*4 + rg;
        const int col = wc*64 + j*16 + lm;
        Dh[(size_t)(r0 + row) * NN + c0 + col] = f2bf(acc[i][j][rg]);
      }
}

// ---------------- fused GJ diag + panel (512 threads, grid 16 x 2mats) ----------------
// Round-10: diag loop = MACRO-4 block Gauss-Jordan — four pivots per barrier epoch via
// analytic 4x4 pivot-block inverse (Schur on 2x2 blocks; SPD). Epochs 64 -> 32.
// Rounds 5-9 established per-epoch fixed cost dominates; same FMA total, same math.
__global__ __launch_bounds__(512) void k_gj_diagpanel(
    float* __restrict__ M0, float* __restrict__ M1,
    float* __restrict__ Pbuf, ushort* __restrict__ Pth, ushort* __restrict__ Ptl,
    float* __restrict__ Tf, ushort* __restrict__ Tth, ushort* __restrict__ Ttl,
    ushort* __restrict__ Chh, ushort* __restrict__ Chl, int kb){
  __shared__ float Ps[128 * 132];
  __shared__ __align__(16) float rowbufD[2][4][144];  // [parity][pivot row 0..3][group-padded cols]
  __shared__ float colbufD[2][4][128];                // [parity][pivot col 0..3][row]
  __shared__ float Bs[2][16 * 132];
  const int mat = blockIdx.y;
  float* M = mat ? M1 : M0;
  float* P = Pbuf + (size_t)mat * NB * NB;
  ushort* Ph = Pth + (size_t)mat * NB * NB;
  ushort* Pl = Ptl + (size_t)mat * NB * NB;
  float* Tfm = Tf + (size_t)mat * NB * NN;
  ushort* Th = Tth + (size_t)mat * NN * NB;
  ushort* Tl = Ttl + (size_t)mat * NN * NB;
  ushort* Ch = Chh + (size_t)mat * NN * NB;
  ushort* Cl = Chl + (size_t)mat * NN * NB;
  const int k0 = kb * NB;
  const int t = threadIdx.x;
  // ---- macro-4 register GJ diag (thread (r=t>>2, g=t&3) owns cols [g*32, g*32+32)) ----
  {
    const int r = t >> 2, g = t & 3;
    float reg[32];
    const float* mrow = M + (size_t)(k0 + r) * NN + k0 + g*32;
    #pragma unroll
    for (int u = 0; u < 8; u++){
      float4 v = ((const float4*)mrow)[u];
      reg[4*u+0]=v.x; reg[4*u+1]=v.y; reg[4*u+2]=v.z; reg[4*u+3]=v.w;
    }
    // prologue: publish raw rows 0..3 (parity 0) and multiplier cols 0..3
    if (r < 4){
      #pragma unroll
      for (int u = 0; u < 8; u++)
        *(float4*)&rowbufD[0][r][g*36 + 4*u] =
            make_float4(reg[4*u], reg[4*u+1], reg[4*u+2], reg[4*u+3]);
    }
    if (g == 0){
      colbufD[0][0][r] = reg[0]; colbufD[0][1][r] = reg[1];
      colbufD[0][2][r] = reg[2]; colbufD[0][3][r] = reg[3];
    }
    __syncthreads();
    #pragma unroll 1
    for (int m = 0; m < NB/4; m++){
      const int pj = m & 1, pn = pj ^ 1;
      const int pc0 = 4*m;
      const int pg = pc0 >> 5, pe = pc0 & 31;
      // read 4x4 pivot block (LDS broadcast)
      float Pb_[4][4];
      #pragma unroll
      for (int i = 0; i < 4; i++)
        #pragma unroll
        for (int j = 0; j < 4; j++)
          Pb_[i][j] = rowbufD[pj][i][pg*36 + pe + j];
      // analytic 4x4 inverse via Schur on 2x2 blocks (SPD => invertible blocks)
      float I16[4][4];
      {
        const float a00=Pb_[0][0], a01=Pb_[0][1], a10=Pb_[1][0], a11=Pb_[1][1];
        const float b00=Pb_[0][2], b01=Pb_[0][3], b10=Pb_[1][2], b11=Pb_[1][3];
        const float c00=Pb_[2][0], c01=Pb_[2][1], c10=Pb_[3][0], c11=Pb_[3][1];
        const float d00=Pb_[2][2], d01=Pb_[2][3], d10=Pb_[3][2], d11=Pb_[3][3];
        const float rda = 1.0f / (a00*a11 - a01*a10);
        const float Ai00 =  a11*rda, Ai01 = -a01*rda;
        const float Ai10 = -a10*rda, Ai11 =  a00*rda;
        // CAi = C*Ai ; AiB = Ai*B
        const float CA00 = c00*Ai00 + c01*Ai10, CA01 = c00*Ai01 + c01*Ai11;
        const float CA10 = c10*Ai00 + c11*Ai10, CA11 = c10*Ai01 + c11*Ai11;
        const float AB00 = Ai00*b00 + Ai01*b10, AB01 = Ai00*b01 + Ai01*b11;
        const float AB10 = Ai10*b00 + Ai11*b10, AB11 = Ai10*b01 + Ai11*b11;
        // S = D - CAi*B
        const float S00 = d00 - (CA00*b00 + CA01*b10);
        const float S01 = d01 - (CA00*b01 + CA01*b11);
        const float S10 = d10 - (CA10*b00 + CA11*b10);
        const float S11 = d11 - (CA10*b01 + CA11*b11);
        const float rds = 1.0f / (S00*S11 - S01*S10);
        const float Si00 =  S11*rds, Si01 = -S01*rds;
        const float Si10 = -S10*rds, Si11 =  S00*rds;
        // X = AiB*Si ; L = -Si*CAi ; T = Ai + X*CAi ; R = -X
        const float X00 = AB00*Si00 + AB01*Si10, X01 = AB00*Si01 + AB01*Si11;
        const float X10 = AB10*Si00 + AB11*Si10, X11 = AB10*Si01 + AB11*Si11;
        I16[0][0] = Ai00 + (X00*CA00 + X01*CA10);
        I16[0][1] = Ai01 + (X00*CA01 + X01*CA11);
        I16[1][0] = Ai10 + (X10*CA00 + X11*CA10);
        I16[1][1] = Ai11 + (X10*CA01 + X11*CA11);
        I16[0][2] = -X00; I16[0][3] = -X01;
        I16[1][2] = -X10; I16[1][3] = -X11;
        I16[2][0] = -(Si00*CA00 + Si01*CA10);
        I16[2][1] = -(Si00*CA01 + Si01*CA11);
        I16[3][0] = -(Si10*CA00 + Si11*CA10);
        I16[3][1] = -(Si10*CA01 + Si11*CA11);
        I16[2][2] = Si00; I16[2][3] = Si01;
        I16[3][2] = Si10; I16[3][3] = Si11;
      }
      const int rl = r - pc0;
      if (rl >= 0 && rl < 4){
        // pivot rows: new row = I16[rl][:] * raw rows; pivot cols overridden with I16
        const float m0 = (rl==0)?I16[0][0]:(rl==1)?I16[1][0]:(rl==2)?I16[2][0]:I16[3][0];
        const float m1 = (rl==0)?I16[0][1]:(rl==1)?I16[1][1]:(rl==2)?I16[2][1]:I16[3][1];
        const float m2 = (rl==0)?I16[0][2]:(rl==1)?I16[1][2]:(rl==2)?I16[2][2]:I16[3][2];
        const float m3 = (rl==0)?I16[0][3]:(rl==1)?I16[1][3]:(rl==2)?I16[2][3]:I16[3][3];
        #pragma unroll
        for (int u = 0; u < 8; u++){
          float4 r0v = *(const float4*)&rowbufD[pj][0][g*36 + 4*u];
          float4 r1v = *(const float4*)&rowbufD[pj][1][g*36 + 4*u];
          float4 r2v = *(const float4*)&rowbufD[pj][2][g*36 + 4*u];
          float4 r3v = *(const float4*)&rowbufD[pj][3][g*36 + 4*u];
          #pragma unroll
          for (int e = 0; e < 4; e++){
            const int c = g*32 + 4*u + e;
            const float w0 = (e==0)?r0v.x:(e==1)?r0v.y:(e==2)?r0v.z:r0v.w;
            const float w1 = (e==0)?r1v.x:(e==1)?r1v.y:(e==2)?r1v.z:r1v.w;
            const float w2 = (e==0)?r2v.x:(e==1)?r2v.y:(e==2)?r2v.z:r2v.w;
            const float w3 = (e==0)?r3v.x:(e==1)?r3v.y:(e==2)?r3v.z:r3v.w;
            float nv = m0*w0 + m1*w1 + m2*w2 + m3*w3;
            if (c == pc0+0) nv = m0;
            if (c == pc0+1) nv = m1;
            if (c == pc0+2) nv = m2;
            if (c == pc0+3) nv = m3;
            reg[4*u+e] = nv;
          }
        }
      } else {
        const float w0 = colbufD[pj][0][r], w1 = colbufD[pj][1][r];
        const float w2 = colbufD[pj][2][r], w3 = colbufD[pj][3][r];
        const float f0 = w0*I16[0][0] + w1*I16[1][0] + w2*I16[2][0] + w3*I16[3][0];
        const float f1 = w0*I16[0][1] + w1*I16[1][1] + w2*I16[2][1] + w3*I16[3][1];
        const float f2 = w0*I16[0][2] + w1*I16[1][2] + w2*I16[2][2] + w3*I16[3][2];
        const float f3 = w0*I16[0][3] + w1*I16[1][3] + w2*I16[2][3] + w3*I16[3][3];
        #pragma unroll
        for (int u = 0; u < 8; u++){
          float4 r0v = *(const float4*)&rowbufD[pj][0][g*36 + 4*u];
          float4 r1v = *(const float4*)&rowbufD[pj][1][g*36 + 4*u];
          float4 r2v = *(const float4*)&rowbufD[pj][2][g*36 + 4*u];
          float4 r3v = *(const float4*)&rowbufD[pj][3][g*36 + 4*u];
          #pragma unroll
          for (int e = 0; e < 4; e++){
            const int c = g*32 + 4*u + e;
            const float q0 = (e==0)?r0v.x:(e==1)?r0v.y:(e==2)?r0v.z:r0v.w;
            const float q1 = (e==0)?r1v.x:(e==1)?r1v.y:(e==2)?r1v.z:r1v.w;
            const float q2 = (e==0)?r2v.x:(e==1)?r2v.y:(e==2)?r2v.z:r2v.w;
            const float q3 = (e==0)?r3v.x:(e==1)?r3v.y:(e==2)?r3v.z:r3v.w;
            float nv = fmaf(-f3, q3, fmaf(-f2, q2, fmaf(-f1, q1, fmaf(-f0, q0, reg[4*u+e]))));
            if (c == pc0+0) nv = -f0;
            if (c == pc0+1) nv = -f1;
            if (c == pc0+2) nv = -f2;
            if (c == pc0+3) nv = -f3;
            reg[4*u+e] = nv;
          }
        }
      }
      // publish next epoch's raw rows/cols (post-update, parity pn)
      if (m + 1 < NB/4){
        const int pc0n = pc0 + 4;
        if (g == (pc0n >> 5)){
          const int pen = pc0n & 31;
          #pragma unroll
          for (int e2 = 0; e2 < 32; e2++){
            if (e2 == pen+0) colbufD[pn][0][r] = reg[e2];
            if (e2 == pen+1) colbufD[pn][1][r] = reg[e2];
            if (e2 == pen+2) colbufD[pn][2][r] = reg[e2];
            if (e2 == pen+3) colbufD[pn][3][r] = reg[e2];
          }
        }
        if (r >= pc0n && r < pc0n + 4){
          const int k = r - pc0n;
          #pragma unroll
          for (int u = 0; u < 8; u++)
            *(float4*)&rowbufD[pn][k][g*36 + 4*u] =
                make_float4(reg[4*u], reg[4*u+1], reg[4*u+2], reg[4*u+3]);
        }
      }
      __syncthreads();
    }
    // write P into Ps (and fp32 P for block 0) — vector stores, strip layout
    #pragma unroll
    for (int u = 0; u < 8; u++)
      *(float4*)&Ps[r*132 + g*32 + 4*u] =
          make_float4(reg[4*u], reg[4*u+1], reg[4*u+2], reg[4*u+3]);
    if (blockIdx.x == 0){
      #pragma unroll
      for (int u = 0; u < 8; u++)
        *(float4*)&P[r*NB + g*32 + 4*u] =
            make_float4(reg[4*u], reg[4*u+1], reg[4*u+2], reg[4*u+3]);
    }
  }
  __syncthreads();
  // ---- coalesced Ph/Pl writeout from Ps (block 0 only) ----
  if (blockIdx.x == 0){
    const int c = t >> 2, rbp = (t & 3) * 32;
    #pragma unroll
    for (int q4 = 0; q4 < 8; q4++){
      ushort h4[4], l4[4];
      #pragma unroll
      for (int e = 0; e < 4; e++){
        float v = Ps[(rbp + q4*4 + e)*132 + c];
        ushort h = f2bf(v);
        h4[e] = h; l4[e] = f2bf(v - bf2f(h));
      }
      *(ushort4*)(Ph + (size_t)c * NB + rbp + q4*4) = make_ushort4(h4[0], h4[1], h4[2], h4[3]);
      *(ushort4*)(Pl + (size_t)c * NB + rbp + q4*4) = make_ushort4(l4[0], l4[1], l4[2], l4[3]);
    }
  }
  // ---- panel GEMM: 2 j-tiles per block, one per 256-thread half ----
  const int half = t >> 8, tt = t & 255;
  const int j0 = blockIdx.x * 256 + half * 128;
  { // C split copy of M[:, kcol] panel (rows j0..j0+127) - pre-update values
    const int row = tt >> 1, hc = (tt & 1) * 64;
    const float* src = M + (size_t)(j0 + row) * NN + k0 + hc;
    ushort* dh = Ch + (size_t)(j0 + row) * NB + hc;
    ushort* dl = Cl + (size_t)(j0 + row) * NB + hc;
    #pragma unroll
    for (int u = 0; u < 16; u++){
      float4 v = ((const float4*)src)[u];
      ushort h0 = f2bf(v.x), h1 = f2bf(v.y), h2 = f2bf(v.z), h3 = f2bf(v.w);
      ((ushort4*)dh)[u] = make_ushort4(h0, h1, h2, h3);
      ((ushort4*)dl)[u] = make_ushort4(f2bf(v.x - bf2f(h0)), f2bf(v.y - bf2f(h1)),
                                       f2bf(v.z - bf2f(h2)), f2bf(v.w - bf2f(h3)));
    }
  }
  const int tx = tt & 15, ty = tt >> 4;
  float* myBs = Bs[half];
  float acc[8][8];
  #pragma unroll
  for (int u = 0; u < 8; u++)
    #pragma unroll
    for (int v = 0; v < 8; v++) acc[u][v] = 0.f;
  for (int ks = 0; ks < NB; ks += 16){
    {
      const int kkl = tt >> 4, c8 = (tt & 15) * 8;
      const float* pb = M + (size_t)(k0 + ks + kkl) * NN + j0 + c8;
      float4 b0 = ((const float4*)pb)[0];
      float4 b1 = ((const float4*)pb)[1];
      *(float4*)&myBs[kkl*132 + c8]     = b0;
      *(float4*)&myBs[kkl*132 + c8 + 4] = b1;
    }
    __syncthreads();
    #pragma unroll
    for (int kk = 0; kk < 16; kk++){
      float a[8], b[8];
      #pragma unroll
      for (int u = 0; u < 8; u++) a[u] = Ps[RMAP(ty,u)*132 + ks + kk];
      float4 b0 = *(const float4*)&myBs[kk*132 + tx*4];
      float4 b1 = *(const float4*)&myBs[kk*132 + tx*4 + 64];
      b[0]=b0.x; b[1]=b0.y; b[2]=b0.z; b[3]=b0.w;
      b[4]=b1.x; b[5]=b1.y; b[6]=b1.z; b[7]=b1.w;
      #pragma unroll
      for (int u = 0; u < 8; u++)
        #pragma unroll
        for (int v = 0; v < 8; v++) acc[u][v] += a[u] * b[v];
    }
    __syncthreads();
  }
  // write T fp32 (coalesced) + T transposed split
  #pragma unroll
  for (int u = 0; u < 8; u++){
    const int rr = RMAP(ty,u);
    float* pd = Tfm + (size_t)rr * NN + j0 + tx*4;
    *(float4*)pd        = make_float4(acc[u][0], acc[u][1], acc[u][2], acc[u][3]);
    *(float4*)(pd + 64) = make_float4(acc[u][4], acc[u][5], acc[u][6], acc[u][7]);
    #pragma unroll
    for (int v = 0; v < 8; v++){
      const int cc = j0 + CMAP(tx,v);
      float val = acc[u][v];
      ushort h = f2bf(val);
      Th[(size_t)cc * NB + rr] = h;
      Tl[(size_t)cc * NB + rr] = f2bf(val - bf2f(h));
    }
  }
}

// Trailing update (MFMA split-3) + chunked LDS-transpose epilogue (33.8 KB LDS -> 4 blk/CU)
__global__ __launch_bounds__(256) void k_gj_update(float* __restrict__ M0, float* __restrict__ M1,
    const float* __restrict__ Pbuf,
    const ushort* __restrict__ Pth, const ushort* __restrict__ Ptl,
    const float* __restrict__ Tf,
    const ushort* __restrict__ Tth, const ushort* __restrict__ Ttl,
    const ushort* __restrict__ Chh, const ushort* __restrict__ Chl, int kb){
  __shared__ __align__(16) float shchunk[64 * 132];   // 33.8 KB; staging aliased below (32 KB)
  ushort* tAh = (ushort*)shchunk;
  ushort* tAl = tAh + 4096;
  ushort* tBh = tAl + 4096;
  ushort* tBl = tBh + 4096;
  const int mat = blockIdx.z;
  float* M = mat ? M1 : M0;
  const float* P = Pbuf + (size_t)mat * NB * NB;
  const ushort* Ph = Pth + (size_t)mat * NB * NB;
  const ushort* Pl = Ptl + (size_t)mat * NB * NB;
  const float* Tfm = Tf + (size_t)mat * NB * NN;
  const ushort* Th = Tth + (size_t)mat * NN * NB;
  const ushort* Tl = Ttl + (size_t)mat * NN * NB;
  const ushort* Ch = Chh + (size_t)mat * NN * NB;
  const ushort* Cl = Chl + (size_t)mat * NN * NB;
  const int jb = blockIdx.x, ib = blockIdx.y;
  const int k0 = kb * NB, i0 = ib * NB, j0 = jb * NB;
  const int t = threadIdx.x;
  if (ib == kb){
    const int row = t >> 1, half = (t & 1) * 64;
    float* dst = M + (size_t)(k0 + row) * NN + j0 + half;
    if (jb == kb){
      const float* src = P + (size_t)row * NB + half;
      #pragma unroll
      for (int u = 0; u < 16; u++) ((float4*)dst)[u] = ((const float4*)src)[u];
    } else {
      const float* src = Tfm + (size_t)row * NN + j0 + half;
      #pragma unroll
      for (int u = 0; u < 16; u++) ((float4*)dst)[u] = ((const float4*)src)[u];
    }
    return;
  }
  const int L = t & 63, w = t >> 6;
  const int wr = w >> 1, wc = w & 1;
  const int lm = L & 15, quad = L >> 4;
  const int sch = (t & 3) * 8;
  const ushort* Bh = (jb == kb) ? Ph : (Th + (size_t)j0 * NB);
  const ushort* Bl = (jb == kb) ? Pl : (Tl + (size_t)j0 * NB);
  const ushort* Ahp = Ch + (size_t)i0 * NB;
  const ushort* Alp = Cl + (size_t)i0 * NB;
  f32x4 acc[4][4];
  #pragma unroll
  for (int i = 0; i < 4; i++)
    #pragma unroll
    for (int j = 0; j < 4; j++) acc[i][j] = (f32x4){0.f, 0.f, 0.f, 0.f};
  for (int ks = 0; ks < NB; ks += 32){
    #pragma unroll
    for (int p = 0; p < 2; p++){
      const int row = p*64 + (t >> 2);
      const size_t ga = (size_t)row * NB + ks + sch;
      const int lo = row*32 + sch;
      stage16(Ahp + ga, tAh + lo);
      stage16(Alp + ga, tAl + lo);
      stage16(Bh + ga, tBh + lo);
      stage16(Bl + ga, tBl + lo);
    }
    __syncthreads();
    bf16x8 ah[4], al[4], bh[4], bl[4];
    #pragma unroll
    for (int i = 0; i < 4; i++){
      const int ao = (wr*64 + i*16 + lm)*32 + quad*8;
      const int bo = (wc*64 + i*16 + lm)*32 + quad*8;
      ah[i] = *(const bf16x8*)&tAh[ao];
      al[i] = *(const bf16x8*)&tAl[ao];
      bh[i] = *(const bf16x8*)&tBh[bo];
      bl[i] = *(const bf16x8*)&tBl[bo];
    }
    #pragma unroll
    for (int i = 0; i < 4; i++)
      #pragma unroll
      for (int j = 0; j < 4; j++){
        acc[i][j] = __builtin_amdgcn_mfma_f32_16x16x32_bf16(ah[i], bh[j], acc[i][j], 0, 0, 0);
        acc[i][j] = __builtin_amdgcn_mfma_f32_16x16x32_bf16(ah[i], bl[j], acc[i][j], 0, 0, 0);
        acc[i][j] = __builtin_amdgcn_mfma_f32_16x16x32_bf16(al[i], bh[j], acc[i][j], 0, 0, 0);
      }
    __syncthreads();
  }
  // chunked transpose: 2 passes of 64 rows through 33.8 KB LDS, coalesced float4 RMW
  const int rloc = t >> 2, cg = (t & 3) * 4;
  const int jc0 = (jb == kb) ? k0 : j0;
  #pragma unroll 1
  for (int hp = 0; hp < 2; hp++){
    if (wr == hp){
      #pragma unroll
      for (int i = 0; i < 4; i++)
        #pragma unroll
        for (int j = 0; j < 4; j++)
          #pragma unroll
          for (int rg = 0; rg < 4; rg++){
            const int row = i*16 + quad*4 + rg;       // local 0..63
            const int col = wc*64 + j*16 + lm;
            shchunk[row*132 + col] = acc[i][j][rg];
          }
    }
    __syncthreads();
    float* pm = M + (size_t)(i0 + hp*64 + rloc) * NN + jc0;
    if (jb == kb){
      #pragma unroll
      for (int c = 0; c < 8; c++){
        const int col = cg + 16*c;
        float4 v = *(float4*)&shchunk[rloc*132 + col];
        *(float4*)(pm + col) = make_float4(-v.x, -v.y, -v.z, -v.w);
      }
    } else {
      #pragma unroll
      for (int c = 0; c < 8; c++){
        const int col = cg + 16*c;
        float4 v = *(float4*)&shchunk[rloc*132 + col];
        float4 m = *(float4*)(pm + col);
        m.x -= v.x; m.y -= v.y; m.z -= v.z; m.w -= v.w;
        *(float4*)(pm + col) = m;
      }
    }
    __syncthreads();
  }
}

// ---------------- final combine ----------------
__global__ void k_combine(const float* __restrict__ slots, float* __restrict__ out){
  if (threadIdx.x == 0 && blockIdx.x == 0){
    const double invN2 = 1.0 / ((double)NN * (double)NN);
    double term1 = ((double)slots[0] + (double)slots[1] - 2.0 * (double)slots[2]) * invN2;
    double pairs = 0.0;
    for (int p = 0; p < 3; p++){
      const float* s = slots + 4 + 5 * p;
      pairs += ((double)s[0] - 0.2 * (double)s[1] + (double)s[2] - 0.2 * (double)s[3] - 2.0 * (double)s[4]);
    }
    out[0] = (float)(1.0 * term1 + 500.0 * pairs * invN2);
    out[1] = (float)((double)slots[3] / (2.0 * (double)NN));
  }
}

// ---------------- host ----------------
extern "C" void kernel_launch(void* const* d_in, const int* in_sizes, int n_in,
                              void* d_out, int out_size, void* d_ws, size_t ws_size,
                              hipStream_t stream){
  const float* x    = (const float*)d_in[0];
  const float* z    = (const float*)d_in[1];
  const float* zz   = (const float*)d_in[2];
  const float* xx   = (const float*)d_in[3];
  const float* stdn = (const float*)d_in[4];
  float* out = (float*)d_out;
  float* ws  = (float*)d_ws;

  const size_t NN2 = (size_t)NN * NN;
  float* R0 = ws;
  float* R1 = R0 + NN2;
  float* R2 = R1 + NN2;
  float* PanelF = R2 + NN2;
  ushort* Tth = (ushort*)PanelF;                       // 2 MB
  ushort* Ttl = Tth + 2 * (size_t)NB * NN;
  ushort* Chh = Ttl + 2 * (size_t)NB * NN;
  ushort* Chl = Chh + 2 * (size_t)NB * NN;             // panels total 8 MB
  float* Tf   = (float*)(Chl + 2 * (size_t)NB * NN);   // 4 MB fp32 T (2 mats)
  float* Pb   = Tf + 2 * (size_t)NB * NN;              // fp32 P (2 mats)
  ushort* Pth = (ushort*)(Pb + 2 * (size_t)NB * NB);
  ushort* Ptl = Pth + 2 * (size_t)NB * NB;
  float* slots= (float*)(Ptl + 2 * (size_t)NB * NB);
  float* stdsq= slots + 32;
  float* zrs  = stdsq + NN;
  float* nzz  = zrs + (size_t)NN * NV;
  float* nz8  = nzz + (size_t)NV * NN;
  float* nrmz = nz8 + (size_t)NV * NN;

  ushort* R0h = (ushort*)R0;   // B hi (bf16)
  ushort* R2h = (ushort*)R2;   // A hi (bf16)
  ushort* Vh  = (ushort*)R1;   // V hi (bf16, lower half of R1)
  ushort* QPh = Vh + NN2;      // Kqp bf16 (upper half of R1)

  dim3 g32(NBLK, NBLK);

  k_zero<<<1, 64, 0, stream>>>(slots, 32);
  k_norms<<<(NN * NV) / 256, 256, 0, stream>>>(z, zz, stdn, stdsq, zrs, nzz, nz8);
  k_rownorm<<<NN / 256, 256, 0, stream>>>(nz8, nrmz);
  k_nll<<<1024, 256, 0, stream>>>(x, xx, slots);
  k_sqq<<<NTRI, 256, 0, stream>>>(z, nrmz, slots);
  k_spp_sqp<<<g32, 256, 0, stream>>>(stdn, stdsq, zrs, nrmz, slots);

  const float* zz0 = zz;            const float* z0 = z;
  const float* zz1 = zz + VD;       const float* z1 = z + VD;
  const float* nzz0 = nzz;          const float* nz0 = nz8;
  const float* nzz1 = nzz + NN;     const float* nz1 = nz8 + NN;

  for (int b = 1; b <= 2; b++){
    const float* zzb = zz + b*VD;  const float* nzzb = nzz + (size_t)b*NN;
    const float* zb  = z + b*VD;   const float* nzb  = nz8 + (size_t)b*NN;
    k_rbf<<<g32, 256, 0, stream>>>(zzb, zzb, nzzb, nzzb, 0.2f, R0);
    k_rbf<<<g32, 256, 0, stream>>>(zb,  zb,  nzb,  nzb,  0.2f, R1);
    for (int kb = 0; kb < NBLK; kb++){
      k_gj_diagpanel<<<dim3(16, 2), 512, 0, stream>>>(R0, R1, Pb, Pth, Ptl,
                                                      Tf, Tth, Ttl, Chh, Chl, kb);
      k_gj_update<<<dim3(NBLK, NBLK, 2), 256, 0, stream>>>(R0, R1, Pb, Pth, Ptl,
                                                           Tf, Tth, Ttl, Chh, Chl, kb);
    }
    // bf16 casts: A -> R2h, B -> R0h (B fp32 in R1 dead after)
    k_split<<<16384, 256, 0, stream>>>(R0, R2h);
    k_split<<<16384, 256, 0, stream>>>(R1, R0h);
    // Kqp bf16 precompute: QP[n][l] = k(zz_n, z_l), into upper half of R1
    k_rbf16<<<g32, 256, 0, stream>>>(zzb, zb, nzzb, nzb, QPh);
    // V = B * QP^T (plain bf16 GEMM); dest Vh (lower half of R1)
    k_mfma_gemm<<<g32, 256, 0, stream>>>(R0h, QPh, Vh);
    // trace GEMMs (pure bf16) with fused tr(L*A) reduction
    if (b == 1){
      k_mfma_tr<<<NTRI, 256, 0, stream>>>(R2h, R2h, 1, 1, 1,
                                          zz0, zz0, nzz0, nzz0, 5, 4,
                                          nullptr, nullptr, nullptr, nullptr, 0, 0, slots);
      k_mfma_tr<<<NTRI, 256, 0, stream>>>(R0h, R0h, 1, 1, 1,
                                          z0, z0, nz0, nz0, 7, 6,
                                          nullptr, nullptr, nullptr, nullptr, 0, 0, slots);
      k_mfma_tr<<<g32, 256, 0, stream>>>(R2h, Vh, 0, 0, 1,
                                         zz0, z0, nzz0, nz0, 8, 0,
                                         nullptr, nullptr, nullptr, nullptr, 0, 0, slots);
    } else {
      k_mfma_tr<<<NTRI, 256, 0, stream>>>(R2h, R2h, 1, 1, 2,
                                          zz1, zz1, nzz1, nzz1, 10, 9,
                                          zz0, zz0, nzz0, nzz0, 15, 14, slots);
      k_mfma_tr<<<NTRI, 256, 0, stream>>>(R0h, R0h, 1, 1, 2,
                                          z1, z1, nz1, nz1, 12, 11,
                                          z0, z0, nz0, nz0, 17, 16, slots);
      k_mfma_tr<<<g32, 256, 0, stream>>>(R2h, Vh, 0, 0, 2,
                                         zz1, z1, nzz1, nz1, 13, 0,
                                         zz0, z0, nzz0, nz0, 18, 0, slots);
    }
  }
  k_combine<<<1, 1, 0, stream>>>(slots, out);
}